// Round 11
// baseline (340.488 us; speedup 1.0000x reference)
//
#include <hip/hip_runtime.h>
#include <math.h>

#define NUMR 11
#define NSTEP 64
#define BATCH 8192
#define PDIM 128
#define MC 10000
#define DT (1.0f/64.0f)
#define RDOM 5.0f
#define CAP_EPS 0.1f
#define TP (NSTEP*BATCH)        // 524288

// workspace float offsets
#define OFF_HIST 0              // 220 ints
#define OFF_W3EB 256            // bf16 [t][r][c][8]: o0..5, CT(-DT folded), pad
#define OFF_B3E  180480         // f32 [t][r][8]: o0..5, BC(-DT folded), pad
#define OFF_BT   186112         // f32 [t][r][sa][c]
#define OFF_BB   1087232        // f32 [t][r][sa]
#define OFF_W2A  1101312        // bf16 A-ordered [t][4096]
#define OFF_WF2A 1232384
#define OFF_GEO  1363456        // f32 [t][p][12]
#define OFF_SM   7654912        // f32 [t][p][2] {scale, meta}
#define OFF_CONTRIB 8703488     // f32 [t][p]

typedef __attribute__((ext_vector_type(8))) short short8;   // 8 bf16
typedef __attribute__((ext_vector_type(4))) float f32x4;

__device__ __forceinline__ float tanh_f(float x) {
    float e = __expf(2.0f * x);
    return 1.0f - 2.0f * __builtin_amdgcn_rcpf(e + 1.0f);
}
__device__ __forceinline__ unsigned short bf16bits(float f) {
    unsigned u = __float_as_uint(f);
    return (unsigned short)((u + 0x7FFFu + ((u >> 16) & 1u)) >> 16);
}
__device__ __forceinline__ float bf16f(unsigned short s) {
    return __uint_as_float(((unsigned)s) << 16);
}
// HW packed f32->bf16 (RNE, matches bf16bits on normals; no builtin on gfx950)
__device__ __forceinline__ unsigned cvt_pk_bf16(float lo, float hi) {
    unsigned r;
    asm("v_cvt_pk_bf16_f32 %0, %1, %2" : "=v"(r) : "v"(lo), "v"(hi));
    return r;
}

__device__ __forceinline__ void reflect3(float* p, float* g) {
    float nr = sqrtf(p[0]*p[0] + p[1]*p[1] + p[2]*p[2]);
    if (nr > RDOM) {
        float inv = 1.0f / fmaxf(nr, 1e-12f);   // exact div: trajectory-sensitive
        float nb0 = p[0]*inv, nb1 = p[1]*inv, nb2 = p[2]*inv;
        float sc = 2.0f*RDOM - nr;
        p[0] = nb0*sc; p[1] = nb1*sc; p[2] = nb2*sc;
        #pragma unroll
        for (int j = 0; j < 3; ++j) {
            float proj = nb0*g[j] + nb1*g[3+j] + nb2*g[6+j];
            g[j]   -= 2.0f*nb0*proj;
            g[3+j] -= 2.0f*nb1*proj;
            g[6+j] -= 2.0f*nb2*proj;
        }
    }
}

// =========== K_A: fused prep ==============================================
// [0,128): geom | [128,236): hist | [236,300): pack | [300,4460): tables.
// Geom: 2-step-deep input prefetch (per-step compute ~600cy < HBM ~900cy).
// Tables branch LDS-stages all dot-product inputs; strides padded to 132.
__launch_bounds__(256)
__global__ void k_prep(const int* __restrict__ rt0, const float* __restrict__ xt0,
                       const float* __restrict__ yt0, const float* __restrict__ dBx,
                       const float* __restrict__ dBy, const float* __restrict__ junif,
                       const float* __restrict__ sunif, const float* __restrict__ jm,
                       const float* __restrict__ cr, const float* __restrict__ cfr,
                       const float* __restrict__ mcu,
                       const float* __restrict__ W2, const float* __restrict__ Wf2,
                       const float* __restrict__ W3, const float* __restrict__ b3,
                       const float* __restrict__ emb, const float* __restrict__ Wf3,
                       const float* __restrict__ bf3, const float* __restrict__ jump_r,
                       const float* __restrict__ jump_l,
                       float* ws, int* hist, float* out) {
    // overlaid LDS: tables use 6440 floats; geom uses 242; hist uses 220 ints
    __shared__ float smem[6440];
    int blk = blockIdx.x, tid = threadIdx.x;

    if (blk < 128) {
        // ---------------- geom: 1 particle/thread, 64 working lanes -------
        float* sjm = smem; float* scr = smem + 220; float* smul = smem + 231;
        for (int i = tid; i < 220; i += 256) sjm[i] = jm[i];
        if (tid < 11) { scr[tid] = cr[tid]; smul[tid] = __expf(-cfr[tid]*DT); }
        __syncthreads();
        if (tid >= 64) return;
        int p = blk * 64 + tid;

        int rt = rt0[p];
        float xt[3], xin[3], yin[3], gtx[9], gty[9];
        #pragma unroll
        for (int i = 0; i < 3; ++i) { xt[i] = xt0[p*3+i]; xin[i] = xt[i]; yin[i] = yt0[p*3+i]; }
        #pragma unroll
        for (int i = 0; i < 9; ++i) { gtx[i] = (i % 4 == 0) ? 1.f : 0.f; gty[i] = gtx[i]; }
        float ef = 1.f, run = 1.f;

        // cur = t=0, nxt = t=1 (prefetched); loop issues t+2 at top of t
        float ju = junif[p], su = sunif[p];
        float dbx0 = dBx[(size_t)p*2], dbx1 = dBx[(size_t)p*2+1];
        float dby0 = dBy[(size_t)p*3], dby1 = dBy[(size_t)p*3+1], dby2 = dBy[(size_t)p*3+2];
        float nju=0.f,nsu=0.f,ndbx0=0.f,ndbx1=0.f,ndby0=0.f,ndby1=0.f,ndby2=0.f;
        {
            int nb = BATCH + p;
            nju = junif[nb]; nsu = sunif[nb];
            ndbx0 = dBx[(size_t)nb*2]; ndbx1 = dBx[(size_t)nb*2+1];
            ndby0 = dBy[(size_t)nb*3]; ndby1 = dBy[(size_t)nb*3+1]; ndby2 = dBy[(size_t)nb*3+2];
        }

        float* GEO = ws + OFF_GEO;
        float* SM  = ws + OFF_SM;
        #pragma unroll 1
        for (int t = 0; t < NSTEP; ++t) {
            float mju=0.f,msu=0.f,mdbx0=0.f,mdbx1=0.f,mdby0=0.f,mdby1=0.f,mdby2=0.f;
            if (t < NSTEP-2) {
                int nb = (t+2)*BATCH + p;
                mju = junif[nb]; msu = sunif[nb];
                mdbx0 = dBx[(size_t)nb*2]; mdbx1 = dBx[(size_t)nb*2+1];
                mdby0 = dBy[(size_t)nb*3]; mdby1 = dBy[(size_t)nb*3+1]; mdby2 = dBy[(size_t)nb*3+2];
            }
            int base = t*BATCH + p;
            int r = rt - 10;
            int jon = (ju < scr[r]*DT) ? 1 : 0;
            int cnt = 0;
            #pragma unroll
            for (int j = 0; j < 20; ++j) cnt += (su < sjm[r*20+j]) ? 1 : 0;
            int ind = 20 - cnt;
            int drt = (ind < 10) ? (ind+1) : -(ind-9);
            drt = jon ? drt : 0;
            int sa = (drt > 0) ? (drt-1) : ((drt < 0) ? (9-drt) : 0);
            int jf = (drt != 0) ? 1 : 0;

            float nx = fmaxf(sqrtf(xt[0]*xt[0]+xt[1]*xt[1]+xt[2]*xt[2]), 1e-12f);
            float c = fminf(1.f, fmaxf(-1.f, xt[2]/nx));
            float ct = sqrtf(fmaxf(0.f, 1.f - c*c));
            float st = -c;
            float rxy2 = xt[0]*xt[0] + xt[1]*xt[1];
            float cp = 1.f, sp = 0.f;
            if (rxy2 > 0.f) { float ir = 1.0f/sqrtf(rxy2); cp = xt[0]*ir; sp = xt[1]*ir; }
            float Ti[9];
            Ti[0]=cp*ct; Ti[1]=-sp; Ti[2]=cp*st;
            Ti[3]=sp*ct; Ti[4]=cp;  Ti[5]=sp*st;
            Ti[6]=-st;   Ti[7]=0.f; Ti[8]=ct;

            float sdx = 1.0f/(float)(r+10);
            float scale = run * ef;

            float cx[3], cy[3];
            #pragma unroll
            for (int i = 0; i < 3; ++i) {
                float w31 = gtx[i*3]*Ti[1] + gtx[i*3+1]*Ti[4] + gtx[i*3+2]*Ti[7];
                float w32 = gtx[i*3]*Ti[2] + gtx[i*3+1]*Ti[5] + gtx[i*3+2]*Ti[8];
                cx[i] = sdx * (w31*dbx1 - w32*dbx0);
                cy[i] = gty[i*3]*dby0 + gty[i*3+1]*dby1 + gty[i*3+2]*dby2;
            }
            float* gp = GEO + (size_t)base*12;
            float4 v0 = {xin[0], xin[1], xin[2], yin[0]};
            float4 v1 = {yin[1], yin[2], cx[0], cx[1]};
            float4 v2 = {cx[2], cy[0], cy[1], cy[2]};
            *(float4*)(gp)     = v0;
            *(float4*)(gp + 4) = v1;
            *(float4*)(gp + 8) = v2;
            float2 smv = {scale, __int_as_float(r | (sa<<8) | (jf<<16))};
            *(float2*)(SM + (size_t)base*2) = smv;

            ef *= smul[r];

            // Taylor sin/cos: |dX| <= ~0.075, err ~8e-9
            float dX0 = sdx*dbx0, dX1 = sdx*dbx1;
            float x2 = dX0*dX0, y2 = dX1*dX1;
            float s0 = dX0*(1.f - x2*(1.f/6.f));
            float cc0 = 1.f - x2*0.5f + x2*x2*(1.f/24.f);
            float s1 = dX1*(1.f - y2*(1.f/6.f));
            float cc1 = 1.f - y2*0.5f + y2*y2*(1.f/24.f);
            float cart0 = cc0*cc1 - 1.0f, cart1 = cc0*s1, cart2 = -s0;
            float dX3[3];
            #pragma unroll
            for (int i = 0; i < 3; ++i)
                dX3[i] = Ti[i*3]*cart0 + Ti[i*3+1]*cart1 + Ti[i*3+2]*cart2;
            #pragma unroll
            for (int i = 0; i < 3; ++i) xt[i] += dX3[i];
            #pragma unroll
            for (int i = 0; i < 3; ++i)
                xin[i] += gtx[i*3]*dX3[0] + gtx[i*3+1]*dX3[1] + gtx[i*3+2]*dX3[2];
            #pragma unroll
            for (int i = 0; i < 3; ++i)
                yin[i] += gty[i*3]*dby0 + gty[i*3+1]*dby1 + gty[i*3+2]*dby2;
            rt += drt; rt = (rt < 10) ? 10 : ((rt > 20) ? 20 : rt);
            reflect3(xin, gtx);
            reflect3(yin, gty);
            float d0 = xin[0]-yin[0], d1 = xin[1]-yin[1], d2 = xin[2]-yin[2];
            if (sqrtf(d0*d0 + d1*d1 + d2*d2) < CAP_EPS) run = 0.f;

            ju = nju; su = nsu; dbx0 = ndbx0; dbx1 = ndbx1;
            dby0 = ndby0; dby1 = ndby1; dby2 = ndby2;
            nju = mju; nsu = msu; ndbx0 = mdbx0; ndbx1 = mdbx1;
            ndby0 = mdby0; ndby1 = mdby1; ndby2 = mdby2;
        }
        float d0 = xin[0]-yin[0], d1 = xin[1]-yin[1], d2 = xin[2]-yin[2];
        float u0v = __expf(-(d0*d0 + d1*d1 + d2*d2));
        out[BATCH + p] = run * u0v * ef;

    } else if (blk < 236) {
        // ---------------- hist ----------------
        int* lh = (int*)smem;
        for (int i = tid; i < 220; i += 256) lh[i] = 0;
        __syncthreads();
        int hb = blk - 128;
        #pragma unroll
        for (int j = 0; j < 4; ++j) {
            int i = hb*1024 + j*256 + tid;
            if (i < MC*NUMR) {
                int r = i % NUMR;
                float u = mcu[i];
                int cnt = 0;
                #pragma unroll
                for (int k = 0; k < 20; ++k) cnt += (u < jm[r*20+k]) ? 1 : 0;
                int ind = 20 - cnt;
                int s = (ind < 10) ? (ind+1) : -(ind-9);
                int sa = (s > 0) ? (s-1) : (10 + (-s-1));
                atomicAdd(&lh[r*20+sa], 1);
            }
        }
        __syncthreads();
        if (tid < 220 && lh[tid]) atomicAdd(&hist[tid], lh[tid]);

    } else if (blk < 300) {
        // ---------------- pack W2/Wf2 -> bf16 MFMA-A-lane order -----------
        int t = blk - 236;
        unsigned short* W2A  = (unsigned short*)(ws + OFF_W2A)  + t*4096;
        unsigned short* WF2A = (unsigned short*)(ws + OFF_WF2A) + t*4096;
        for (int i = tid; i < 4096; i += 256) {
            int j = i & 7, L = (i >> 3) & 63, ktct = i >> 9;
            int ct = ktct >> 1, kt = ktct & 1;
            int c = ct*16 + (L & 15);
            int k = kt*32 + (L >> 4)*8 + j;
            W2A[i]  = bf16bits(W2[t*4096 + k*64 + c]);
            WF2A[i] = bf16bits(Wf2[t*4096 + k*64 + c]);
        }

    } else {
        // ---------------- tables (W3E slots 0-5 bf16, B3E, BT, BB) --------
        // LDS-staged inputs; identical FP order to the global-load version.
        int idx = blk - 300;
        int t = idx / 65, kk = idx % 65;
        bool brow = (kk == 64);
        const float* w3row = brow ? (b3 + t*768) : (W3 + (t*64+kk)*768);
        const float* wfrow = brow ? (bf3 + t*128) : (Wf3 + (t*64+kk)*128);
        unsigned short* W3EB = (unsigned short*)(ws + OFF_W3EB);

        float* sW3  = smem;          // 768
        float* sWf  = smem + 768;    // 128
        float* sEmb = smem + 896;    // 11*132 = 1452
        float* sJr  = smem + 2348;   // 11*132 = 1452
        float* sJl  = smem + 3800;   // 20*132 = 2640  (total 6440)
        for (int i = tid; i < 768; i += 256) sW3[i] = w3row[i];
        if (tid < 128) sWf[tid] = wfrow[tid];
        for (int i = tid; i < 1408; i += 256) {
            int r = i >> 7, p = i & 127;
            sEmb[r*132 + p] = emb[(t*11+r)*128 + p];
            sJr[r*132 + p]  = jump_r[i];
        }
        for (int i = tid; i < 2560; i += 256) {
            int sa = i >> 7, p = i & 127;
            sJl[sa*132 + p] = jump_l[i];
        }
        __syncthreads();

        for (int q = tid; q < 286; q += 256) {
            if (q < 66) {
                int o = q / 11, r = q % 11;
                const float* e = sEmb + r*132;
                float a0 = 0.f, a1 = 0.f;
                #pragma unroll 4
                for (int p = 0; p < 128; p += 2) {
                    a0 = fmaf(e[p],   sW3[p*6+o],     a0);
                    a1 = fmaf(e[p+1], sW3[(p+1)*6+o], a1);
                }
                float acc = a0 + a1;
                if (brow) ws[OFF_B3E + (t*11+r)*8 + o] = acc;
                else      W3EB[(size_t)((t*11+r)*64 + kk)*8 + o] = bf16bits(acc);
            } else {
                int qq = q - 66;
                int sa = qq / 11, r = qq % 11;
                const float* jr = sJr + r*132;
                const float* jl = sJl + sa*132;
                float a0 = 0.f, a1 = 0.f;
                #pragma unroll 4
                for (int p = 0; p < 128; p += 2) {
                    a0 = fmaf(sWf[p],   jr[p]   * jl[p],   a0);
                    a1 = fmaf(sWf[p+1], jr[p+1] * jl[p+1], a1);
                }
                float acc = a0 + a1;
                if (brow) ws[OFF_BB + (t*11+r)*20 + sa] = acc;
                else      ws[OFF_BT + ((size_t)(t*11+r)*20 + sa)*64 + kk] = acc;
            }
        }
    }
}

// =========== K_B: CT/BC from MC histogram; -DT folded into CT/BC ==========
__global__ void k_fold(const int* __restrict__ hist, const float* __restrict__ cr,
                       float* ws) {
    int t = blockIdx.x, tid = threadIdx.x;
    unsigned short* W3EB = (unsigned short*)(ws + OFF_W3EB);
    for (int i = tid; i < 715; i += 256) {
        if (i < 704) {
            int r = i >> 6, c = i & 63;
            float crn = cr[r] * (1.0f/(float)MC);
            const float* btp = ws + OFF_BT + (size_t)(t*11+r)*20*64 + c;
            float acc = 0.f;
            #pragma unroll
            for (int sa = 0; sa < 20; ++sa)
                acc += (float)hist[r*20+sa] * btp[sa*64];
            W3EB[(size_t)((t*11+r)*64 + c)*8 + 6] = bf16bits(acc * crn * (-DT));
        } else {
            int r = i - 704;
            float crn = cr[r] * (1.0f/(float)MC);
            float acc = 0.f;
            #pragma unroll
            for (int sa = 0; sa < 20; ++sa)
                acc += (float)hist[r*20+sa] * ws[OFF_BB + (t*11+r)*20 + sa];
            ws[OFF_B3E + (t*11+r)*8 + 6] = acc * crn * (-DT);
        }
    }
}

// =========== K5: MFMA MLP; W2 + r-tables in LDS; 4 blocks/CU ==============
// (256,4) + natural 64 VGPR is the verified sweet spot — do not touch.
// This round: epilogue ILP — dual accumulators (pA/pB), tree-structured s,
// scalar-uint bf16 unpack. Pure f32 scalar reorder (~1e-7), +1-2 VGPR.
__launch_bounds__(256, 4)
__global__ void k_mlp(const float* __restrict__ ws,
                      const float* __restrict__ W1, const float* __restrict__ b1,
                      const float* __restrict__ Wf1, const float* __restrict__ bf1,
                      const float* __restrict__ b2, const float* __restrict__ bf2,
                      float* __restrict__ contrib) {
    __shared__ unsigned short sW2[4096], sWf2[4096];
    __shared__ unsigned short sW3E[11*520];   // r-stride 520 (pad 8)
    __shared__ float sB3E[11*12];
    __shared__ float sBB[220];
    int tid = threadIdx.x;
    int t = blockIdx.x & 63;
    {
        const unsigned* g2  = (const unsigned*)((const unsigned short*)(ws + OFF_W2A)  + t*4096);
        const unsigned* g2f = (const unsigned*)((const unsigned short*)(ws + OFF_WF2A) + t*4096);
        unsigned* s2  = (unsigned*)sW2;
        unsigned* s2f = (unsigned*)sWf2;
        #pragma unroll
        for (int i = 0; i < 8; ++i) {
            s2[i*256 + tid]  = g2[i*256 + tid];
            s2f[i*256 + tid] = g2f[i*256 + tid];
        }
        const unsigned* g3 = (const unsigned*)((const unsigned short*)(ws + OFF_W3EB) + (size_t)t*5632);
        unsigned* s3 = (unsigned*)sW3E;
        for (int i = tid; i < 2816; i += 256) {
            int r = i >> 8, off = i & 255;
            s3[r*260 + off] = g3[i];
        }
        if (tid < 88) {
            int r = tid >> 3, o = tid & 7;
            sB3E[r*12 + o] = ws[OFF_B3E + t*88 + tid];
        }
        if (tid < 220) sBB[tid] = ws[OFF_BB + t*220 + tid];
    }
    __syncthreads();
    int L = tid & 63, l15 = L & 15, q4 = L >> 4;
    int pbase = (blockIdx.x >> 6) * 256 + (tid >> 6) * 64;

    float4 bh4[4], bf4[4];
    #pragma unroll
    for (int ct = 0; ct < 4; ++ct) {
        bh4[ct] = *(const float4*)(b2  + t*64 + ct*16 + q4*4);
        bf4[ct] = *(const float4*)(bf2 + t*64 + ct*16 + q4*4);
    }
    const float* GEO = ws + OFF_GEO;
    const float* SM  = ws + OFF_SM;
    const float* W1t  = W1  + t*384;
    const float* Wf1t = Wf1 + t*384;
    const float* b1t  = b1  + t*64;
    const float* bf1t = bf1 + t*64;

    // prefetch g=0
    int base_n = t*BATCH + pbase + l15;
    float2 sm_n = *(const float2*)(SM + (size_t)base_n*2);
    float4 ga_n = *(const float4*)(GEO + (size_t)base_n*12);
    float4 gb_n = *(const float4*)(GEO + (size_t)base_n*12 + 4);
    float4 gc_n = *(const float4*)(GEO + (size_t)base_n*12 + 8);

    #pragma unroll 1
    for (int g = 0; g < 4; ++g) {
        int base = base_n;
        float2 sm = sm_n;
        float4 ga = ga_n, gb = gb_n, gc = gc_n;
        if (g < 3) {
            base_n = t*BATCH + pbase + (g+1)*16 + l15;
            sm_n = *(const float2*)(SM + (size_t)base_n*2);
            ga_n = *(const float4*)(GEO + (size_t)base_n*12);
            gb_n = *(const float4*)(GEO + (size_t)base_n*12 + 4);
            gc_n = *(const float4*)(GEO + (size_t)base_n*12 + 8);
        }
        float scale = sm.x;
        if (__ballot(scale != 0.f) == 0ULL) {
            if (q4 == 0) contrib[base] = 0.f;
            continue;
        }
        int meta = __float_as_int(sm.y);
        float inp[6]  = {ga.x, ga.y, ga.z, ga.w, gb.x, gb.y};
        float coef[6] = {gb.z, gb.w, gc.x, gc.y, gc.z, gc.w};
        int r = meta & 255, sa = (meta >> 8) & 255;
        bool jump = ((meta >> 16) & 1) != 0;

        // L1 -> B-fragments (B[k=q4*8+j][n=l15])
        short8 bh[2], bfr[2];
        #pragma unroll
        for (int kt = 0; kt < 2; ++kt) {
            int kb = kt*32 + q4*8;
            float av[8], fv[8];
            #pragma unroll
            for (int j = 0; j < 8; ++j) { av[j] = b1t[kb+j]; fv[j] = bf1t[kb+j]; }
            #pragma unroll
            for (int i = 0; i < 6; ++i) {
                float x = inp[i];
                #pragma unroll
                for (int j = 0; j < 8; ++j) {
                    av[j] = fmaf(x, W1t[i*64 + kb + j],  av[j]);
                    fv[j] = fmaf(x, Wf1t[i*64 + kb + j], fv[j]);
                }
            }
            short8 vh, vf;
            unsigned* vhp = (unsigned*)&vh;
            unsigned* vfp = (unsigned*)&vf;
            #pragma unroll
            for (int j = 0; j < 4; ++j) {
                vhp[j] = cvt_pk_bf16(tanh_f(av[2*j]), tanh_f(av[2*j+1]));
                vfp[j] = cvt_pk_bf16(tanh_f(fv[2*j]), tanh_f(fv[2*j+1]));
            }
            bh[kt] = vh; bfr[kt] = vf;
        }

        const unsigned short* W3E8 = sW3E + r*520;
        const float* btp = ws + OFF_BT + ((size_t)(t*11 + r)*20 + sa)*64;
        float pA = 0.f, pB = 0.f;    // dual accumulators: halves the dep chain
        #pragma unroll
        for (int ct = 0; ct < 4; ++ct) {
            short8 a0 = *(const short8*)(sW2  + ((ct*2 + 0)*64 + L)*8);
            short8 a1 = *(const short8*)(sW2  + ((ct*2 + 1)*64 + L)*8);
            short8 c0 = *(const short8*)(sWf2 + ((ct*2 + 0)*64 + L)*8);
            short8 c1 = *(const short8*)(sWf2 + ((ct*2 + 1)*64 + L)*8);
            // bias as MFMA C-init (D = A*B + C)
            f32x4 acc  = {bh4[ct].x, bh4[ct].y, bh4[ct].z, bh4[ct].w};
            f32x4 accf = {bf4[ct].x, bf4[ct].y, bf4[ct].z, bf4[ct].w};
            acc  = __builtin_amdgcn_mfma_f32_16x16x32_bf16(a0, bh[0],  acc,  0, 0, 0);
            acc  = __builtin_amdgcn_mfma_f32_16x16x32_bf16(a1, bh[1],  acc,  0, 0, 0);
            accf = __builtin_amdgcn_mfma_f32_16x16x32_bf16(c0, bfr[0], accf, 0, 0, 0);
            accf = __builtin_amdgcn_mfma_f32_16x16x32_bf16(c1, bfr[1], accf, 0, 0, 0);
            #pragma unroll
            for (int reg = 0; reg < 4; ++reg) {
                float h2 = tanh_f(acc[reg]);
                float f2 = tanh_f(accf[reg]);
                int c = ct*16 + q4*4 + reg;
                // scalar-uint unpack: 1 op/value, no short extraction
                const unsigned* wp = (const unsigned*)(W3E8 + c*8);
                unsigned u0 = wp[0], u1 = wp[1], u2 = wp[2], u3 = wp[3];
                float s01 = fmaf(__uint_as_float(u0 & 0xffff0000u), coef[1],
                                 __uint_as_float(u0 << 16) * coef[0]);
                float s23 = fmaf(__uint_as_float(u1 & 0xffff0000u), coef[3],
                                 __uint_as_float(u1 << 16) * coef[2]);
                float s45 = fmaf(__uint_as_float(u2 & 0xffff0000u), coef[5],
                                 __uint_as_float(u2 << 16) * coef[4]);
                float s = (s01 + s23) + s45;      // tree: 3-level, not 6
                pA = fmaf(h2, s, pA);
                pB = fmaf(f2, __uint_as_float(u3 << 16), pB);  // CT, -DT folded
                if (jump) pA = fmaf(f2, btp[c], pA);
            }
        }
        float pdp = pA + pB;
        pdp += __shfl_xor(pdp, 16, 64);
        pdp += __shfl_xor(pdp, 32, 64);

        const float* B3E8 = sB3E + r*12;
        float4 ba  = *(const float4*)(B3E8);
        float4 bbv = *(const float4*)(B3E8 + 4);
        float dpart = pdp
            + ((ba.x*coef[0] + ba.y*coef[1]) + (ba.z*coef[2] + ba.w*coef[3]))
            + ((bbv.x*coef[4] + bbv.y*coef[5]) + bbv.z);   // BC, -DT folded
        if (jump) dpart += sBB[r*20 + sa];
        if (q4 == 0) contrib[base] = scale * dpart;
    }
}

// =========== K6: reduce over t ============================================
__global__ void k_reduce(const float* __restrict__ contrib, const float* __restrict__ u,
                         float* out) {
    __shared__ float red[256];
    int tid = threadIdx.x;
    int pi = tid & 31, tc = tid >> 5;
    int p = blockIdx.x * 32 + pi;
    float a = 0.f;
    #pragma unroll
    for (int j = 0; j < 8; ++j) a += contrib[(tc*8 + j)*BATCH + p];
    red[tid] = a;
    __syncthreads();
    if (tid < 32) {
        float s = u[0];
        #pragma unroll
        for (int c = 0; c < 8; ++c) s += red[c*32 + pi];
        out[p] = s;
    }
}

extern "C" void kernel_launch(void* const* d_in, const int* in_sizes, int n_in,
                              void* d_out, int out_size, void* d_ws, size_t ws_size,
                              hipStream_t stream) {
    const float* u      = (const float*)d_in[0];
    const float* jump_r = (const float*)d_in[1];
    const float* jump_l = (const float*)d_in[2];
    const float* W1  = (const float*)d_in[3];
    const float* b1  = (const float*)d_in[4];
    const float* W2  = (const float*)d_in[5];
    const float* b2  = (const float*)d_in[6];
    const float* W3  = (const float*)d_in[7];
    const float* b3  = (const float*)d_in[8];
    const float* emb = (const float*)d_in[9];
    const float* Wf1 = (const float*)d_in[10];
    const float* bf1 = (const float*)d_in[11];
    const float* Wf2 = (const float*)d_in[12];
    const float* bf2 = (const float*)d_in[13];
    const float* Wf3 = (const float*)d_in[14];
    const float* bf3 = (const float*)d_in[15];
    const int*   rt0 = (const int*)d_in[16];
    const float* xt0 = (const float*)d_in[17];
    const float* yt0 = (const float*)d_in[18];
    const float* dBx = (const float*)d_in[19];
    const float* dBy = (const float*)d_in[20];
    const float* junif = (const float*)d_in[21];
    const float* sunif = (const float*)d_in[22];
    const float* mcu = (const float*)d_in[23];
    const float* jm  = (const float*)d_in[24];
    const float* cr  = (const float*)d_in[25];
    const float* cfr = (const float*)d_in[26];
    float* ws  = (float*)d_ws;
    float* out = (float*)d_out;

    hipMemsetAsync(ws + OFF_HIST, 0, 220*sizeof(int), stream);
    k_prep<<<4460, 256, 0, stream>>>(rt0, xt0, yt0, dBx, dBy, junif, sunif,
                                     jm, cr, cfr, mcu, W2, Wf2,
                                     W3, b3, emb, Wf3, bf3, jump_r, jump_l,
                                     ws, (int*)(ws + OFF_HIST), out);
    k_fold<<<64, 256, 0, stream>>>((const int*)(ws + OFF_HIST), cr, ws);
    k_mlp<<<2048, 256, 0, stream>>>(ws, W1, b1, Wf1, bf1, b2, bf2,
                                    ws + OFF_CONTRIB);
    k_reduce<<<256, 256, 0, stream>>>(ws + OFF_CONTRIB, u, out);
}

// Round 12
// 286.728 us; speedup vs baseline: 1.1875x; 1.1875x over previous
//
#include <hip/hip_runtime.h>
#include <math.h>

#define NUMR 11
#define NSTEP 64
#define BATCH 8192
#define PDIM 128
#define MC 10000
#define DT (1.0f/64.0f)
#define RDOM 5.0f
#define CAP_EPS 0.1f
#define TP (NSTEP*BATCH)        // 524288

// workspace float offsets
#define OFF_HIST 0              // 220 ints
#define OFF_W3EB 256            // bf16 [t][r][c][8]: o0..5, CT(-DT folded), pad
#define OFF_B3E  180480         // f32 [t][r][8]: o0..5, BC(-DT folded), pad
#define OFF_BT   186112         // f32 [t][r][sa][c]
#define OFF_BB   1087232        // f32 [t][r][sa]
#define OFF_W2A  1101312        // bf16 A-ordered [t][4096]
#define OFF_WF2A 1232384
#define OFF_GEO  1363456        // f32 [t][p][12]
#define OFF_SM   7654912        // f32 [t][p][2] {scale, meta}
#define OFF_CONTRIB 8703488     // f32 [t][p]

typedef __attribute__((ext_vector_type(8))) short short8;   // 8 bf16
typedef __attribute__((ext_vector_type(4))) float f32x4;

__device__ __forceinline__ float tanh_f(float x) {
    float e = __expf(2.0f * x);
    return 1.0f - 2.0f * __builtin_amdgcn_rcpf(e + 1.0f);
}
__device__ __forceinline__ unsigned short bf16bits(float f) {
    unsigned u = __float_as_uint(f);
    return (unsigned short)((u + 0x7FFFu + ((u >> 16) & 1u)) >> 16);
}
__device__ __forceinline__ float bf16f(unsigned short s) {
    return __uint_as_float(((unsigned)s) << 16);
}
// HW packed f32->bf16 (RNE, matches bf16bits on normals; no builtin on gfx950)
__device__ __forceinline__ unsigned cvt_pk_bf16(float lo, float hi) {
    unsigned r;
    asm("v_cvt_pk_bf16_f32 %0, %1, %2" : "=v"(r) : "v"(lo), "v"(hi));
    return r;
}

__device__ __forceinline__ void reflect3(float* p, float* g) {
    float nr = sqrtf(p[0]*p[0] + p[1]*p[1] + p[2]*p[2]);
    if (nr > RDOM) {
        float inv = 1.0f / fmaxf(nr, 1e-12f);   // exact div: trajectory-sensitive
        float nb0 = p[0]*inv, nb1 = p[1]*inv, nb2 = p[2]*inv;
        float sc = 2.0f*RDOM - nr;
        p[0] = nb0*sc; p[1] = nb1*sc; p[2] = nb2*sc;
        #pragma unroll
        for (int j = 0; j < 3; ++j) {
            float proj = nb0*g[j] + nb1*g[3+j] + nb2*g[6+j];
            g[j]   -= 2.0f*nb0*proj;
            g[3+j] -= 2.0f*nb1*proj;
            g[6+j] -= 2.0f*nb2*proj;
        }
    }
}

// =========== K_A: fused prep ==============================================
// [0,128): geom | [128,236): hist | [236,300): pack | [300,4460): tables.
// Geom: 2-step-deep input prefetch (per-step compute ~600cy < HBM ~900cy).
// Tables branch LDS-stages all dot-product inputs; strides padded to 132.
__launch_bounds__(256)
__global__ void k_prep(const int* __restrict__ rt0, const float* __restrict__ xt0,
                       const float* __restrict__ yt0, const float* __restrict__ dBx,
                       const float* __restrict__ dBy, const float* __restrict__ junif,
                       const float* __restrict__ sunif, const float* __restrict__ jm,
                       const float* __restrict__ cr, const float* __restrict__ cfr,
                       const float* __restrict__ mcu,
                       const float* __restrict__ W2, const float* __restrict__ Wf2,
                       const float* __restrict__ W3, const float* __restrict__ b3,
                       const float* __restrict__ emb, const float* __restrict__ Wf3,
                       const float* __restrict__ bf3, const float* __restrict__ jump_r,
                       const float* __restrict__ jump_l,
                       float* ws, int* hist, float* out) {
    // overlaid LDS: tables use 6440 floats; geom uses 242; hist uses 220 ints
    __shared__ float smem[6440];
    int blk = blockIdx.x, tid = threadIdx.x;

    if (blk < 128) {
        // ---------------- geom: 1 particle/thread, 64 working lanes -------
        float* sjm = smem; float* scr = smem + 220; float* smul = smem + 231;
        for (int i = tid; i < 220; i += 256) sjm[i] = jm[i];
        if (tid < 11) { scr[tid] = cr[tid]; smul[tid] = __expf(-cfr[tid]*DT); }
        __syncthreads();
        if (tid >= 64) return;
        int p = blk * 64 + tid;

        int rt = rt0[p];
        float xt[3], xin[3], yin[3], gtx[9], gty[9];
        #pragma unroll
        for (int i = 0; i < 3; ++i) { xt[i] = xt0[p*3+i]; xin[i] = xt[i]; yin[i] = yt0[p*3+i]; }
        #pragma unroll
        for (int i = 0; i < 9; ++i) { gtx[i] = (i % 4 == 0) ? 1.f : 0.f; gty[i] = gtx[i]; }
        float ef = 1.f, run = 1.f;

        // cur = t=0, nxt = t=1 (prefetched); loop issues t+2 at top of t
        float ju = junif[p], su = sunif[p];
        float dbx0 = dBx[(size_t)p*2], dbx1 = dBx[(size_t)p*2+1];
        float dby0 = dBy[(size_t)p*3], dby1 = dBy[(size_t)p*3+1], dby2 = dBy[(size_t)p*3+2];
        float nju=0.f,nsu=0.f,ndbx0=0.f,ndbx1=0.f,ndby0=0.f,ndby1=0.f,ndby2=0.f;
        {
            int nb = BATCH + p;
            nju = junif[nb]; nsu = sunif[nb];
            ndbx0 = dBx[(size_t)nb*2]; ndbx1 = dBx[(size_t)nb*2+1];
            ndby0 = dBy[(size_t)nb*3]; ndby1 = dBy[(size_t)nb*3+1]; ndby2 = dBy[(size_t)nb*3+2];
        }

        float* GEO = ws + OFF_GEO;
        float* SM  = ws + OFF_SM;
        #pragma unroll 1
        for (int t = 0; t < NSTEP; ++t) {
            float mju=0.f,msu=0.f,mdbx0=0.f,mdbx1=0.f,mdby0=0.f,mdby1=0.f,mdby2=0.f;
            if (t < NSTEP-2) {
                int nb = (t+2)*BATCH + p;
                mju = junif[nb]; msu = sunif[nb];
                mdbx0 = dBx[(size_t)nb*2]; mdbx1 = dBx[(size_t)nb*2+1];
                mdby0 = dBy[(size_t)nb*3]; mdby1 = dBy[(size_t)nb*3+1]; mdby2 = dBy[(size_t)nb*3+2];
            }
            int base = t*BATCH + p;
            int r = rt - 10;
            int jon = (ju < scr[r]*DT) ? 1 : 0;
            int cnt = 0;
            #pragma unroll
            for (int j = 0; j < 20; ++j) cnt += (su < sjm[r*20+j]) ? 1 : 0;
            int ind = 20 - cnt;
            int drt = (ind < 10) ? (ind+1) : -(ind-9);
            drt = jon ? drt : 0;
            int sa = (drt > 0) ? (drt-1) : ((drt < 0) ? (9-drt) : 0);
            int jf = (drt != 0) ? 1 : 0;

            float nx = fmaxf(sqrtf(xt[0]*xt[0]+xt[1]*xt[1]+xt[2]*xt[2]), 1e-12f);
            float c = fminf(1.f, fmaxf(-1.f, xt[2]/nx));
            float ct = sqrtf(fmaxf(0.f, 1.f - c*c));
            float st = -c;
            float rxy2 = xt[0]*xt[0] + xt[1]*xt[1];
            float cp = 1.f, sp = 0.f;
            if (rxy2 > 0.f) { float ir = 1.0f/sqrtf(rxy2); cp = xt[0]*ir; sp = xt[1]*ir; }
            float Ti[9];
            Ti[0]=cp*ct; Ti[1]=-sp; Ti[2]=cp*st;
            Ti[3]=sp*ct; Ti[4]=cp;  Ti[5]=sp*st;
            Ti[6]=-st;   Ti[7]=0.f; Ti[8]=ct;

            float sdx = 1.0f/(float)(r+10);
            float scale = run * ef;

            float cx[3], cy[3];
            #pragma unroll
            for (int i = 0; i < 3; ++i) {
                float w31 = gtx[i*3]*Ti[1] + gtx[i*3+1]*Ti[4] + gtx[i*3+2]*Ti[7];
                float w32 = gtx[i*3]*Ti[2] + gtx[i*3+1]*Ti[5] + gtx[i*3+2]*Ti[8];
                cx[i] = sdx * (w31*dbx1 - w32*dbx0);
                cy[i] = gty[i*3]*dby0 + gty[i*3+1]*dby1 + gty[i*3+2]*dby2;
            }
            float* gp = GEO + (size_t)base*12;
            float4 v0 = {xin[0], xin[1], xin[2], yin[0]};
            float4 v1 = {yin[1], yin[2], cx[0], cx[1]};
            float4 v2 = {cx[2], cy[0], cy[1], cy[2]};
            *(float4*)(gp)     = v0;
            *(float4*)(gp + 4) = v1;
            *(float4*)(gp + 8) = v2;
            float2 smv = {scale, __int_as_float(r | (sa<<8) | (jf<<16))};
            *(float2*)(SM + (size_t)base*2) = smv;

            ef *= smul[r];

            // Taylor sin/cos: |dX| <= ~0.075, err ~8e-9
            float dX0 = sdx*dbx0, dX1 = sdx*dbx1;
            float x2 = dX0*dX0, y2 = dX1*dX1;
            float s0 = dX0*(1.f - x2*(1.f/6.f));
            float cc0 = 1.f - x2*0.5f + x2*x2*(1.f/24.f);
            float s1 = dX1*(1.f - y2*(1.f/6.f));
            float cc1 = 1.f - y2*0.5f + y2*y2*(1.f/24.f);
            float cart0 = cc0*cc1 - 1.0f, cart1 = cc0*s1, cart2 = -s0;
            float dX3[3];
            #pragma unroll
            for (int i = 0; i < 3; ++i)
                dX3[i] = Ti[i*3]*cart0 + Ti[i*3+1]*cart1 + Ti[i*3+2]*cart2;
            #pragma unroll
            for (int i = 0; i < 3; ++i) xt[i] += dX3[i];
            #pragma unroll
            for (int i = 0; i < 3; ++i)
                xin[i] += gtx[i*3]*dX3[0] + gtx[i*3+1]*dX3[1] + gtx[i*3+2]*dX3[2];
            #pragma unroll
            for (int i = 0; i < 3; ++i)
                yin[i] += gty[i*3]*dby0 + gty[i*3+1]*dby1 + gty[i*3+2]*dby2;
            rt += drt; rt = (rt < 10) ? 10 : ((rt > 20) ? 20 : rt);
            reflect3(xin, gtx);
            reflect3(yin, gty);
            float d0 = xin[0]-yin[0], d1 = xin[1]-yin[1], d2 = xin[2]-yin[2];
            if (sqrtf(d0*d0 + d1*d1 + d2*d2) < CAP_EPS) run = 0.f;

            ju = nju; su = nsu; dbx0 = ndbx0; dbx1 = ndbx1;
            dby0 = ndby0; dby1 = ndby1; dby2 = ndby2;
            nju = mju; nsu = msu; ndbx0 = mdbx0; ndbx1 = mdbx1;
            ndby0 = mdby0; ndby1 = mdby1; ndby2 = mdby2;
        }
        float d0 = xin[0]-yin[0], d1 = xin[1]-yin[1], d2 = xin[2]-yin[2];
        float u0v = __expf(-(d0*d0 + d1*d1 + d2*d2));
        out[BATCH + p] = run * u0v * ef;

    } else if (blk < 236) {
        // ---------------- hist ----------------
        int* lh = (int*)smem;
        for (int i = tid; i < 220; i += 256) lh[i] = 0;
        __syncthreads();
        int hb = blk - 128;
        #pragma unroll
        for (int j = 0; j < 4; ++j) {
            int i = hb*1024 + j*256 + tid;
            if (i < MC*NUMR) {
                int r = i % NUMR;
                float u = mcu[i];
                int cnt = 0;
                #pragma unroll
                for (int k = 0; k < 20; ++k) cnt += (u < jm[r*20+k]) ? 1 : 0;
                int ind = 20 - cnt;
                int s = (ind < 10) ? (ind+1) : -(ind-9);
                int sa = (s > 0) ? (s-1) : (10 + (-s-1));
                atomicAdd(&lh[r*20+sa], 1);
            }
        }
        __syncthreads();
        if (tid < 220 && lh[tid]) atomicAdd(&hist[tid], lh[tid]);

    } else if (blk < 300) {
        // ---------------- pack W2/Wf2 -> bf16 MFMA-A-lane order -----------
        int t = blk - 236;
        unsigned short* W2A  = (unsigned short*)(ws + OFF_W2A)  + t*4096;
        unsigned short* WF2A = (unsigned short*)(ws + OFF_WF2A) + t*4096;
        for (int i = tid; i < 4096; i += 256) {
            int j = i & 7, L = (i >> 3) & 63, ktct = i >> 9;
            int ct = ktct >> 1, kt = ktct & 1;
            int c = ct*16 + (L & 15);
            int k = kt*32 + (L >> 4)*8 + j;
            W2A[i]  = bf16bits(W2[t*4096 + k*64 + c]);
            WF2A[i] = bf16bits(Wf2[t*4096 + k*64 + c]);
        }

    } else {
        // ---------------- tables (W3E slots 0-5 bf16, B3E, BT, BB) --------
        // LDS-staged inputs; identical FP order to the global-load version.
        int idx = blk - 300;
        int t = idx / 65, kk = idx % 65;
        bool brow = (kk == 64);
        const float* w3row = brow ? (b3 + t*768) : (W3 + (t*64+kk)*768);
        const float* wfrow = brow ? (bf3 + t*128) : (Wf3 + (t*64+kk)*128);
        unsigned short* W3EB = (unsigned short*)(ws + OFF_W3EB);

        float* sW3  = smem;          // 768
        float* sWf  = smem + 768;    // 128
        float* sEmb = smem + 896;    // 11*132 = 1452
        float* sJr  = smem + 2348;   // 11*132 = 1452
        float* sJl  = smem + 3800;   // 20*132 = 2640  (total 6440)
        for (int i = tid; i < 768; i += 256) sW3[i] = w3row[i];
        if (tid < 128) sWf[tid] = wfrow[tid];
        for (int i = tid; i < 1408; i += 256) {
            int r = i >> 7, p = i & 127;
            sEmb[r*132 + p] = emb[(t*11+r)*128 + p];
            sJr[r*132 + p]  = jump_r[i];
        }
        for (int i = tid; i < 2560; i += 256) {
            int sa = i >> 7, p = i & 127;
            sJl[sa*132 + p] = jump_l[i];
        }
        __syncthreads();

        for (int q = tid; q < 286; q += 256) {
            if (q < 66) {
                int o = q / 11, r = q % 11;
                const float* e = sEmb + r*132;
                float a0 = 0.f, a1 = 0.f;
                #pragma unroll 4
                for (int p = 0; p < 128; p += 2) {
                    a0 = fmaf(e[p],   sW3[p*6+o],     a0);
                    a1 = fmaf(e[p+1], sW3[(p+1)*6+o], a1);
                }
                float acc = a0 + a1;
                if (brow) ws[OFF_B3E + (t*11+r)*8 + o] = acc;
                else      W3EB[(size_t)((t*11+r)*64 + kk)*8 + o] = bf16bits(acc);
            } else {
                int qq = q - 66;
                int sa = qq / 11, r = qq % 11;
                const float* jr = sJr + r*132;
                const float* jl = sJl + sa*132;
                float a0 = 0.f, a1 = 0.f;
                #pragma unroll 4
                for (int p = 0; p < 128; p += 2) {
                    a0 = fmaf(sWf[p],   jr[p]   * jl[p],   a0);
                    a1 = fmaf(sWf[p+1], jr[p+1] * jl[p+1], a1);
                }
                float acc = a0 + a1;
                if (brow) ws[OFF_BB + (t*11+r)*20 + sa] = acc;
                else      ws[OFF_BT + ((size_t)(t*11+r)*20 + sa)*64 + kk] = acc;
            }
        }
    }
}

// =========== K_B: CT/BC from MC histogram; -DT folded into CT/BC ==========
__global__ void k_fold(const int* __restrict__ hist, const float* __restrict__ cr,
                       float* ws) {
    int t = blockIdx.x, tid = threadIdx.x;
    unsigned short* W3EB = (unsigned short*)(ws + OFF_W3EB);
    for (int i = tid; i < 715; i += 256) {
        if (i < 704) {
            int r = i >> 6, c = i & 63;
            float crn = cr[r] * (1.0f/(float)MC);
            const float* btp = ws + OFF_BT + (size_t)(t*11+r)*20*64 + c;
            float acc = 0.f;
            #pragma unroll
            for (int sa = 0; sa < 20; ++sa)
                acc += (float)hist[r*20+sa] * btp[sa*64];
            W3EB[(size_t)((t*11+r)*64 + c)*8 + 6] = bf16bits(acc * crn * (-DT));
        } else {
            int r = i - 704;
            float crn = cr[r] * (1.0f/(float)MC);
            float acc = 0.f;
            #pragma unroll
            for (int sa = 0; sa < 20; ++sa)
                acc += (float)hist[r*20+sa] * ws[OFF_BB + (t*11+r)*20 + sa];
            ws[OFF_B3E + (t*11+r)*8 + 6] = acc * crn * (-DT);
        }
    }
}

// =========== K5: MFMA MLP; W2 + r-tables in LDS; 4 blocks/CU ==============
// Round-10 exact body (verified 111.4us; zero-live-state rule: r1/r2/r11 all
// spilled when temps were added). This round: grid 2048->1024 (one resident
// generation at 4/CU), g loop 4->8 — staging amortized 2x, no new live state.
__launch_bounds__(256, 4)
__global__ void k_mlp(const float* __restrict__ ws,
                      const float* __restrict__ W1, const float* __restrict__ b1,
                      const float* __restrict__ Wf1, const float* __restrict__ bf1,
                      const float* __restrict__ b2, const float* __restrict__ bf2,
                      float* __restrict__ contrib) {
    __shared__ unsigned short sW2[4096], sWf2[4096];
    __shared__ unsigned short sW3E[11*520];   // r-stride 520 (pad 8)
    __shared__ float sB3E[11*12];
    __shared__ float sBB[220];
    int tid = threadIdx.x;
    int t = blockIdx.x & 63;
    {
        const unsigned* g2  = (const unsigned*)((const unsigned short*)(ws + OFF_W2A)  + t*4096);
        const unsigned* g2f = (const unsigned*)((const unsigned short*)(ws + OFF_WF2A) + t*4096);
        unsigned* s2  = (unsigned*)sW2;
        unsigned* s2f = (unsigned*)sWf2;
        #pragma unroll
        for (int i = 0; i < 8; ++i) {
            s2[i*256 + tid]  = g2[i*256 + tid];
            s2f[i*256 + tid] = g2f[i*256 + tid];
        }
        const unsigned* g3 = (const unsigned*)((const unsigned short*)(ws + OFF_W3EB) + (size_t)t*5632);
        unsigned* s3 = (unsigned*)sW3E;
        for (int i = tid; i < 2816; i += 256) {
            int r = i >> 8, off = i & 255;
            s3[r*260 + off] = g3[i];
        }
        if (tid < 88) {
            int r = tid >> 3, o = tid & 7;
            sB3E[r*12 + o] = ws[OFF_B3E + t*88 + tid];
        }
        if (tid < 220) sBB[tid] = ws[OFF_BB + t*220 + tid];
    }
    __syncthreads();
    int L = tid & 63, l15 = L & 15, q4 = L >> 4;
    int pbase = (blockIdx.x >> 6) * 512 + (tid >> 6) * 128;

    float4 bh4[4], bf4[4];
    #pragma unroll
    for (int ct = 0; ct < 4; ++ct) {
        bh4[ct] = *(const float4*)(b2  + t*64 + ct*16 + q4*4);
        bf4[ct] = *(const float4*)(bf2 + t*64 + ct*16 + q4*4);
    }
    const float* GEO = ws + OFF_GEO;
    const float* SM  = ws + OFF_SM;
    const float* W1t  = W1  + t*384;
    const float* Wf1t = Wf1 + t*384;
    const float* b1t  = b1  + t*64;
    const float* bf1t = bf1 + t*64;

    // prefetch g=0
    int base_n = t*BATCH + pbase + l15;
    float2 sm_n = *(const float2*)(SM + (size_t)base_n*2);
    float4 ga_n = *(const float4*)(GEO + (size_t)base_n*12);
    float4 gb_n = *(const float4*)(GEO + (size_t)base_n*12 + 4);
    float4 gc_n = *(const float4*)(GEO + (size_t)base_n*12 + 8);

    #pragma unroll 1
    for (int g = 0; g < 8; ++g) {
        int base = base_n;
        float2 sm = sm_n;
        float4 ga = ga_n, gb = gb_n, gc = gc_n;
        if (g < 7) {
            base_n = t*BATCH + pbase + (g+1)*16 + l15;
            sm_n = *(const float2*)(SM + (size_t)base_n*2);
            ga_n = *(const float4*)(GEO + (size_t)base_n*12);
            gb_n = *(const float4*)(GEO + (size_t)base_n*12 + 4);
            gc_n = *(const float4*)(GEO + (size_t)base_n*12 + 8);
        }
        float scale = sm.x;
        if (__ballot(scale != 0.f) == 0ULL) {
            if (q4 == 0) contrib[base] = 0.f;
            continue;
        }
        int meta = __float_as_int(sm.y);
        float inp[6]  = {ga.x, ga.y, ga.z, ga.w, gb.x, gb.y};
        float coef[6] = {gb.z, gb.w, gc.x, gc.y, gc.z, gc.w};
        int r = meta & 255, sa = (meta >> 8) & 255;
        bool jump = ((meta >> 16) & 1) != 0;

        // L1 -> B-fragments (B[k=q4*8+j][n=l15])
        short8 bh[2], bfr[2];
        #pragma unroll
        for (int kt = 0; kt < 2; ++kt) {
            int kb = kt*32 + q4*8;
            float av[8], fv[8];
            #pragma unroll
            for (int j = 0; j < 8; ++j) { av[j] = b1t[kb+j]; fv[j] = bf1t[kb+j]; }
            #pragma unroll
            for (int i = 0; i < 6; ++i) {
                float x = inp[i];
                #pragma unroll
                for (int j = 0; j < 8; ++j) {
                    av[j] = fmaf(x, W1t[i*64 + kb + j],  av[j]);
                    fv[j] = fmaf(x, Wf1t[i*64 + kb + j], fv[j]);
                }
            }
            short8 vh, vf;
            unsigned* vhp = (unsigned*)&vh;
            unsigned* vfp = (unsigned*)&vf;
            #pragma unroll
            for (int j = 0; j < 4; ++j) {
                vhp[j] = cvt_pk_bf16(tanh_f(av[2*j]), tanh_f(av[2*j+1]));
                vfp[j] = cvt_pk_bf16(tanh_f(fv[2*j]), tanh_f(fv[2*j+1]));
            }
            bh[kt] = vh; bfr[kt] = vf;
        }

        const unsigned short* W3E8 = sW3E + r*520;
        const float* btp = ws + OFF_BT + ((size_t)(t*11 + r)*20 + sa)*64;
        float pdp = 0.f;
        #pragma unroll
        for (int ct = 0; ct < 4; ++ct) {
            short8 a0 = *(const short8*)(sW2  + ((ct*2 + 0)*64 + L)*8);
            short8 a1 = *(const short8*)(sW2  + ((ct*2 + 1)*64 + L)*8);
            short8 c0 = *(const short8*)(sWf2 + ((ct*2 + 0)*64 + L)*8);
            short8 c1 = *(const short8*)(sWf2 + ((ct*2 + 1)*64 + L)*8);
            // bias as MFMA C-init (D = A*B + C): kills the post-MFMA adds
            f32x4 acc  = {bh4[ct].x, bh4[ct].y, bh4[ct].z, bh4[ct].w};
            f32x4 accf = {bf4[ct].x, bf4[ct].y, bf4[ct].z, bf4[ct].w};
            acc  = __builtin_amdgcn_mfma_f32_16x16x32_bf16(a0, bh[0],  acc,  0, 0, 0);
            acc  = __builtin_amdgcn_mfma_f32_16x16x32_bf16(a1, bh[1],  acc,  0, 0, 0);
            accf = __builtin_amdgcn_mfma_f32_16x16x32_bf16(c0, bfr[0], accf, 0, 0, 0);
            accf = __builtin_amdgcn_mfma_f32_16x16x32_bf16(c1, bfr[1], accf, 0, 0, 0);
            #pragma unroll
            for (int reg = 0; reg < 4; ++reg) {
                float h2 = tanh_f(acc[reg]);
                float f2 = tanh_f(accf[reg]);
                int c = ct*16 + q4*4 + reg;
                short8 wv = *(const short8*)(W3E8 + c*8);
                float s = bf16f((unsigned short)wv[0])*coef[0]
                        + bf16f((unsigned short)wv[1])*coef[1]
                        + bf16f((unsigned short)wv[2])*coef[2]
                        + bf16f((unsigned short)wv[3])*coef[3]
                        + bf16f((unsigned short)wv[4])*coef[4]
                        + bf16f((unsigned short)wv[5])*coef[5];
                pdp = fmaf(h2, s, pdp);
                pdp = fmaf(f2, bf16f((unsigned short)wv[6]), pdp);   // CT, -DT pre-folded
                if (jump) pdp = fmaf(f2, btp[c], pdp);
            }
        }
        pdp += __shfl_xor(pdp, 16, 64);
        pdp += __shfl_xor(pdp, 32, 64);

        const float* B3E8 = sB3E + r*12;
        float4 ba  = *(const float4*)(B3E8);
        float4 bbv = *(const float4*)(B3E8 + 4);
        float dpart = pdp
            + ba.x*coef[0] + ba.y*coef[1] + ba.z*coef[2]
            + ba.w*coef[3] + bbv.x*coef[4] + bbv.y*coef[5]
            + bbv.z;                                   // BC, -DT pre-folded
        if (jump) dpart += sBB[r*20 + sa];
        if (q4 == 0) contrib[base] = scale * dpart;
    }
}

// =========== K6: reduce over t ============================================
__global__ void k_reduce(const float* __restrict__ contrib, const float* __restrict__ u,
                         float* out) {
    __shared__ float red[256];
    int tid = threadIdx.x;
    int pi = tid & 31, tc = tid >> 5;
    int p = blockIdx.x * 32 + pi;
    float a = 0.f;
    #pragma unroll
    for (int j = 0; j < 8; ++j) a += contrib[(tc*8 + j)*BATCH + p];
    red[tid] = a;
    __syncthreads();
    if (tid < 32) {
        float s = u[0];
        #pragma unroll
        for (int c = 0; c < 8; ++c) s += red[c*32 + pi];
        out[p] = s;
    }
}

extern "C" void kernel_launch(void* const* d_in, const int* in_sizes, int n_in,
                              void* d_out, int out_size, void* d_ws, size_t ws_size,
                              hipStream_t stream) {
    const float* u      = (const float*)d_in[0];
    const float* jump_r = (const float*)d_in[1];
    const float* jump_l = (const float*)d_in[2];
    const float* W1  = (const float*)d_in[3];
    const float* b1  = (const float*)d_in[4];
    const float* W2  = (const float*)d_in[5];
    const float* b2  = (const float*)d_in[6];
    const float* W3  = (const float*)d_in[7];
    const float* b3  = (const float*)d_in[8];
    const float* emb = (const float*)d_in[9];
    const float* Wf1 = (const float*)d_in[10];
    const float* bf1 = (const float*)d_in[11];
    const float* Wf2 = (const float*)d_in[12];
    const float* bf2 = (const float*)d_in[13];
    const float* Wf3 = (const float*)d_in[14];
    const float* bf3 = (const float*)d_in[15];
    const int*   rt0 = (const int*)d_in[16];
    const float* xt0 = (const float*)d_in[17];
    const float* yt0 = (const float*)d_in[18];
    const float* dBx = (const float*)d_in[19];
    const float* dBy = (const float*)d_in[20];
    const float* junif = (const float*)d_in[21];
    const float* sunif = (const float*)d_in[22];
    const float* mcu = (const float*)d_in[23];
    const float* jm  = (const float*)d_in[24];
    const float* cr  = (const float*)d_in[25];
    const float* cfr = (const float*)d_in[26];
    float* ws  = (float*)d_ws;
    float* out = (float*)d_out;

    hipMemsetAsync(ws + OFF_HIST, 0, 220*sizeof(int), stream);
    k_prep<<<4460, 256, 0, stream>>>(rt0, xt0, yt0, dBx, dBy, junif, sunif,
                                     jm, cr, cfr, mcu, W2, Wf2,
                                     W3, b3, emb, Wf3, bf3, jump_r, jump_l,
                                     ws, (int*)(ws + OFF_HIST), out);
    k_fold<<<64, 256, 0, stream>>>((const int*)(ws + OFF_HIST), cr, ws);
    k_mlp<<<1024, 256, 0, stream>>>(ws, W1, b1, Wf1, bf1, b2, bf2,
                                    ws + OFF_CONTRIB);
    k_reduce<<<256, 256, 0, stream>>>(ws + OFF_CONTRIB, u, out);
}

// Round 13
// 285.843 us; speedup vs baseline: 1.1912x; 1.0031x over previous
//
#include <hip/hip_runtime.h>
#include <math.h>

#define NUMR 11
#define NSTEP 64
#define BATCH 8192
#define PDIM 128
#define MC 10000
#define DT (1.0f/64.0f)
#define RDOM 5.0f
#define CAP_EPS 0.1f
#define TP (NSTEP*BATCH)        // 524288

// workspace float offsets
#define OFF_HIST 0              // 220 ints
#define OFF_W3EB 256            // bf16 [t][r][c][8]: o0..5, CT(-DT folded), pad
#define OFF_B3E  180480         // f32 [t][r][8]: o0..5, BC(-DT folded), pad
#define OFF_BT   186112         // f32 [t][r][sa][c]
#define OFF_BB   1087232        // f32 [t][r][sa]
#define OFF_W2A  1101312        // bf16 A-ordered [t][4096]
#define OFF_WF2A 1232384
#define OFF_GEO  1363456        // f32 [t][p][12]
#define OFF_SM   7654912        // f32 [t][p][2] {scale, meta}
#define OFF_CONTRIB 8703488     // f32 [t][p]

typedef __attribute__((ext_vector_type(8))) short short8;   // 8 bf16
typedef __attribute__((ext_vector_type(4))) float f32x4;

__device__ __forceinline__ float tanh_f(float x) {
    float e = __expf(2.0f * x);
    return 1.0f - 2.0f * __builtin_amdgcn_rcpf(e + 1.0f);
}
__device__ __forceinline__ unsigned short bf16bits(float f) {
    unsigned u = __float_as_uint(f);
    return (unsigned short)((u + 0x7FFFu + ((u >> 16) & 1u)) >> 16);
}
__device__ __forceinline__ float bf16f(unsigned short s) {
    return __uint_as_float(((unsigned)s) << 16);
}
// HW packed f32->bf16 (RNE, matches bf16bits on normals; no builtin on gfx950)
__device__ __forceinline__ unsigned cvt_pk_bf16(float lo, float hi) {
    unsigned r;
    asm("v_cvt_pk_bf16_f32 %0, %1, %2" : "=v"(r) : "v"(lo), "v"(hi));
    return r;
}

__device__ __forceinline__ void reflect3(float* p, float* g) {
    float nr = sqrtf(p[0]*p[0] + p[1]*p[1] + p[2]*p[2]);
    if (nr > RDOM) {
        float inv = 1.0f / fmaxf(nr, 1e-12f);   // exact div: trajectory-sensitive
        float nb0 = p[0]*inv, nb1 = p[1]*inv, nb2 = p[2]*inv;
        float sc = 2.0f*RDOM - nr;
        p[0] = nb0*sc; p[1] = nb1*sc; p[2] = nb2*sc;
        #pragma unroll
        for (int j = 0; j < 3; ++j) {
            float proj = nb0*g[j] + nb1*g[3+j] + nb2*g[6+j];
            g[j]   -= 2.0f*nb0*proj;
            g[3+j] -= 2.0f*nb1*proj;
            g[6+j] -= 2.0f*nb2*proj;
        }
    }
}

// =========== K_A: fused prep ==============================================
// [0,128): geom | [128,236): hist | [236,300): pack | [300,4460): tables.
// Geom: 2-step-deep input prefetch (per-step compute ~600cy < HBM ~900cy).
// Tables branch LDS-stages all dot-product inputs; strides padded to 132.
__launch_bounds__(256)
__global__ void k_prep(const int* __restrict__ rt0, const float* __restrict__ xt0,
                       const float* __restrict__ yt0, const float* __restrict__ dBx,
                       const float* __restrict__ dBy, const float* __restrict__ junif,
                       const float* __restrict__ sunif, const float* __restrict__ jm,
                       const float* __restrict__ cr, const float* __restrict__ cfr,
                       const float* __restrict__ mcu,
                       const float* __restrict__ W2, const float* __restrict__ Wf2,
                       const float* __restrict__ W3, const float* __restrict__ b3,
                       const float* __restrict__ emb, const float* __restrict__ Wf3,
                       const float* __restrict__ bf3, const float* __restrict__ jump_r,
                       const float* __restrict__ jump_l,
                       float* ws, int* hist, float* out) {
    // overlaid LDS: tables use 6440 floats; geom uses 242; hist uses 220 ints
    __shared__ float smem[6440];
    int blk = blockIdx.x, tid = threadIdx.x;

    if (blk < 128) {
        // ---------------- geom: 1 particle/thread, 64 working lanes -------
        float* sjm = smem; float* scr = smem + 220; float* smul = smem + 231;
        for (int i = tid; i < 220; i += 256) sjm[i] = jm[i];
        if (tid < 11) { scr[tid] = cr[tid]; smul[tid] = __expf(-cfr[tid]*DT); }
        __syncthreads();
        if (tid >= 64) return;
        int p = blk * 64 + tid;

        int rt = rt0[p];
        float xt[3], xin[3], yin[3], gtx[9], gty[9];
        #pragma unroll
        for (int i = 0; i < 3; ++i) { xt[i] = xt0[p*3+i]; xin[i] = xt[i]; yin[i] = yt0[p*3+i]; }
        #pragma unroll
        for (int i = 0; i < 9; ++i) { gtx[i] = (i % 4 == 0) ? 1.f : 0.f; gty[i] = gtx[i]; }
        float ef = 1.f, run = 1.f;

        // cur = t=0, nxt = t=1 (prefetched); loop issues t+2 at top of t
        float ju = junif[p], su = sunif[p];
        float dbx0 = dBx[(size_t)p*2], dbx1 = dBx[(size_t)p*2+1];
        float dby0 = dBy[(size_t)p*3], dby1 = dBy[(size_t)p*3+1], dby2 = dBy[(size_t)p*3+2];
        float nju=0.f,nsu=0.f,ndbx0=0.f,ndbx1=0.f,ndby0=0.f,ndby1=0.f,ndby2=0.f;
        {
            int nb = BATCH + p;
            nju = junif[nb]; nsu = sunif[nb];
            ndbx0 = dBx[(size_t)nb*2]; ndbx1 = dBx[(size_t)nb*2+1];
            ndby0 = dBy[(size_t)nb*3]; ndby1 = dBy[(size_t)nb*3+1]; ndby2 = dBy[(size_t)nb*3+2];
        }

        float* GEO = ws + OFF_GEO;
        float* SM  = ws + OFF_SM;
        #pragma unroll 1
        for (int t = 0; t < NSTEP; ++t) {
            float mju=0.f,msu=0.f,mdbx0=0.f,mdbx1=0.f,mdby0=0.f,mdby1=0.f,mdby2=0.f;
            if (t < NSTEP-2) {
                int nb = (t+2)*BATCH + p;
                mju = junif[nb]; msu = sunif[nb];
                mdbx0 = dBx[(size_t)nb*2]; mdbx1 = dBx[(size_t)nb*2+1];
                mdby0 = dBy[(size_t)nb*3]; mdby1 = dBy[(size_t)nb*3+1]; mdby2 = dBy[(size_t)nb*3+2];
            }
            int base = t*BATCH + p;
            int r = rt - 10;
            int jon = (ju < scr[r]*DT) ? 1 : 0;
            int cnt = 0;
            #pragma unroll
            for (int j = 0; j < 20; ++j) cnt += (su < sjm[r*20+j]) ? 1 : 0;
            int ind = 20 - cnt;
            int drt = (ind < 10) ? (ind+1) : -(ind-9);
            drt = jon ? drt : 0;
            int sa = (drt > 0) ? (drt-1) : ((drt < 0) ? (9-drt) : 0);
            int jf = (drt != 0) ? 1 : 0;

            float nx = fmaxf(sqrtf(xt[0]*xt[0]+xt[1]*xt[1]+xt[2]*xt[2]), 1e-12f);
            float c = fminf(1.f, fmaxf(-1.f, xt[2]/nx));
            float ct = sqrtf(fmaxf(0.f, 1.f - c*c));
            float st = -c;
            float rxy2 = xt[0]*xt[0] + xt[1]*xt[1];
            float cp = 1.f, sp = 0.f;
            if (rxy2 > 0.f) { float ir = 1.0f/sqrtf(rxy2); cp = xt[0]*ir; sp = xt[1]*ir; }
            float Ti[9];
            Ti[0]=cp*ct; Ti[1]=-sp; Ti[2]=cp*st;
            Ti[3]=sp*ct; Ti[4]=cp;  Ti[5]=sp*st;
            Ti[6]=-st;   Ti[7]=0.f; Ti[8]=ct;

            float sdx = 1.0f/(float)(r+10);
            float scale = run * ef;

            float cx[3], cy[3];
            #pragma unroll
            for (int i = 0; i < 3; ++i) {
                float w31 = gtx[i*3]*Ti[1] + gtx[i*3+1]*Ti[4] + gtx[i*3+2]*Ti[7];
                float w32 = gtx[i*3]*Ti[2] + gtx[i*3+1]*Ti[5] + gtx[i*3+2]*Ti[8];
                cx[i] = sdx * (w31*dbx1 - w32*dbx0);
                cy[i] = gty[i*3]*dby0 + gty[i*3+1]*dby1 + gty[i*3+2]*dby2;
            }
            float* gp = GEO + (size_t)base*12;
            float4 v0 = {xin[0], xin[1], xin[2], yin[0]};
            float4 v1 = {yin[1], yin[2], cx[0], cx[1]};
            float4 v2 = {cx[2], cy[0], cy[1], cy[2]};
            *(float4*)(gp)     = v0;
            *(float4*)(gp + 4) = v1;
            *(float4*)(gp + 8) = v2;
            float2 smv = {scale, __int_as_float(r | (sa<<8) | (jf<<16))};
            *(float2*)(SM + (size_t)base*2) = smv;

            ef *= smul[r];

            // Taylor sin/cos: |dX| <= ~0.075, err ~8e-9
            float dX0 = sdx*dbx0, dX1 = sdx*dbx1;
            float x2 = dX0*dX0, y2 = dX1*dX1;
            float s0 = dX0*(1.f - x2*(1.f/6.f));
            float cc0 = 1.f - x2*0.5f + x2*x2*(1.f/24.f);
            float s1 = dX1*(1.f - y2*(1.f/6.f));
            float cc1 = 1.f - y2*0.5f + y2*y2*(1.f/24.f);
            float cart0 = cc0*cc1 - 1.0f, cart1 = cc0*s1, cart2 = -s0;
            float dX3[3];
            #pragma unroll
            for (int i = 0; i < 3; ++i)
                dX3[i] = Ti[i*3]*cart0 + Ti[i*3+1]*cart1 + Ti[i*3+2]*cart2;
            #pragma unroll
            for (int i = 0; i < 3; ++i) xt[i] += dX3[i];
            #pragma unroll
            for (int i = 0; i < 3; ++i)
                xin[i] += gtx[i*3]*dX3[0] + gtx[i*3+1]*dX3[1] + gtx[i*3+2]*dX3[2];
            #pragma unroll
            for (int i = 0; i < 3; ++i)
                yin[i] += gty[i*3]*dby0 + gty[i*3+1]*dby1 + gty[i*3+2]*dby2;
            rt += drt; rt = (rt < 10) ? 10 : ((rt > 20) ? 20 : rt);
            reflect3(xin, gtx);
            reflect3(yin, gty);
            float d0 = xin[0]-yin[0], d1 = xin[1]-yin[1], d2 = xin[2]-yin[2];
            if (sqrtf(d0*d0 + d1*d1 + d2*d2) < CAP_EPS) run = 0.f;

            ju = nju; su = nsu; dbx0 = ndbx0; dbx1 = ndbx1;
            dby0 = ndby0; dby1 = ndby1; dby2 = ndby2;
            nju = mju; nsu = msu; ndbx0 = mdbx0; ndbx1 = mdbx1;
            ndby0 = mdby0; ndby1 = mdby1; ndby2 = mdby2;
        }
        float d0 = xin[0]-yin[0], d1 = xin[1]-yin[1], d2 = xin[2]-yin[2];
        float u0v = __expf(-(d0*d0 + d1*d1 + d2*d2));
        out[BATCH + p] = run * u0v * ef;

    } else if (blk < 236) {
        // ---------------- hist ----------------
        int* lh = (int*)smem;
        for (int i = tid; i < 220; i += 256) lh[i] = 0;
        __syncthreads();
        int hb = blk - 128;
        #pragma unroll
        for (int j = 0; j < 4; ++j) {
            int i = hb*1024 + j*256 + tid;
            if (i < MC*NUMR) {
                int r = i % NUMR;
                float u = mcu[i];
                int cnt = 0;
                #pragma unroll
                for (int k = 0; k < 20; ++k) cnt += (u < jm[r*20+k]) ? 1 : 0;
                int ind = 20 - cnt;
                int s = (ind < 10) ? (ind+1) : -(ind-9);
                int sa = (s > 0) ? (s-1) : (10 + (-s-1));
                atomicAdd(&lh[r*20+sa], 1);
            }
        }
        __syncthreads();
        if (tid < 220 && lh[tid]) atomicAdd(&hist[tid], lh[tid]);

    } else if (blk < 300) {
        // ---------------- pack W2/Wf2 -> bf16 MFMA-A-lane order -----------
        int t = blk - 236;
        unsigned short* W2A  = (unsigned short*)(ws + OFF_W2A)  + t*4096;
        unsigned short* WF2A = (unsigned short*)(ws + OFF_WF2A) + t*4096;
        for (int i = tid; i < 4096; i += 256) {
            int j = i & 7, L = (i >> 3) & 63, ktct = i >> 9;
            int ct = ktct >> 1, kt = ktct & 1;
            int c = ct*16 + (L & 15);
            int k = kt*32 + (L >> 4)*8 + j;
            W2A[i]  = bf16bits(W2[t*4096 + k*64 + c]);
            WF2A[i] = bf16bits(Wf2[t*4096 + k*64 + c]);
        }

    } else {
        // ---------------- tables (W3E slots 0-5 bf16, B3E, BT, BB) --------
        // LDS-staged inputs; identical FP order to the global-load version.
        int idx = blk - 300;
        int t = idx / 65, kk = idx % 65;
        bool brow = (kk == 64);
        const float* w3row = brow ? (b3 + t*768) : (W3 + (t*64+kk)*768);
        const float* wfrow = brow ? (bf3 + t*128) : (Wf3 + (t*64+kk)*128);
        unsigned short* W3EB = (unsigned short*)(ws + OFF_W3EB);

        float* sW3  = smem;          // 768
        float* sWf  = smem + 768;    // 128
        float* sEmb = smem + 896;    // 11*132 = 1452
        float* sJr  = smem + 2348;   // 11*132 = 1452
        float* sJl  = smem + 3800;   // 20*132 = 2640  (total 6440)
        for (int i = tid; i < 768; i += 256) sW3[i] = w3row[i];
        if (tid < 128) sWf[tid] = wfrow[tid];
        for (int i = tid; i < 1408; i += 256) {
            int r = i >> 7, p = i & 127;
            sEmb[r*132 + p] = emb[(t*11+r)*128 + p];
            sJr[r*132 + p]  = jump_r[i];
        }
        for (int i = tid; i < 2560; i += 256) {
            int sa = i >> 7, p = i & 127;
            sJl[sa*132 + p] = jump_l[i];
        }
        __syncthreads();

        for (int q = tid; q < 286; q += 256) {
            if (q < 66) {
                int o = q / 11, r = q % 11;
                const float* e = sEmb + r*132;
                float a0 = 0.f, a1 = 0.f;
                #pragma unroll 4
                for (int p = 0; p < 128; p += 2) {
                    a0 = fmaf(e[p],   sW3[p*6+o],     a0);
                    a1 = fmaf(e[p+1], sW3[(p+1)*6+o], a1);
                }
                float acc = a0 + a1;
                if (brow) ws[OFF_B3E + (t*11+r)*8 + o] = acc;
                else      W3EB[(size_t)((t*11+r)*64 + kk)*8 + o] = bf16bits(acc);
            } else {
                int qq = q - 66;
                int sa = qq / 11, r = qq % 11;
                const float* jr = sJr + r*132;
                const float* jl = sJl + sa*132;
                float a0 = 0.f, a1 = 0.f;
                #pragma unroll 4
                for (int p = 0; p < 128; p += 2) {
                    a0 = fmaf(sWf[p],   jr[p]   * jl[p],   a0);
                    a1 = fmaf(sWf[p+1], jr[p+1] * jl[p+1], a1);
                }
                float acc = a0 + a1;
                if (brow) ws[OFF_BB + (t*11+r)*20 + sa] = acc;
                else      ws[OFF_BT + ((size_t)(t*11+r)*20 + sa)*64 + kk] = acc;
            }
        }
    }
}

// =========== K_B: CT/BC from MC histogram; -DT folded into CT/BC ==========
__global__ void k_fold(const int* __restrict__ hist, const float* __restrict__ cr,
                       float* ws) {
    int t = blockIdx.x, tid = threadIdx.x;
    unsigned short* W3EB = (unsigned short*)(ws + OFF_W3EB);
    for (int i = tid; i < 715; i += 256) {
        if (i < 704) {
            int r = i >> 6, c = i & 63;
            float crn = cr[r] * (1.0f/(float)MC);
            const float* btp = ws + OFF_BT + (size_t)(t*11+r)*20*64 + c;
            float acc = 0.f;
            #pragma unroll
            for (int sa = 0; sa < 20; ++sa)
                acc += (float)hist[r*20+sa] * btp[sa*64];
            W3EB[(size_t)((t*11+r)*64 + c)*8 + 6] = bf16bits(acc * crn * (-DT));
        } else {
            int r = i - 704;
            float crn = cr[r] * (1.0f/(float)MC);
            float acc = 0.f;
            #pragma unroll
            for (int sa = 0; sa < 20; ++sa)
                acc += (float)hist[r*20+sa] * ws[OFF_BB + (t*11+r)*20 + sa];
            ws[OFF_B3E + (t*11+r)*8 + 6] = acc * crn * (-DT);
        }
    }
}

// =========== K5: MFMA MLP; W2 + r-tables in LDS; 4 blocks/CU ==============
// Round-10 exact body — session best (285.5us total, k_mlp 111.4us).
// (256,4) + natural 64 VGPR is the verified sweet spot; the body tolerates
// zero additional live state (r1/r2/r11 all spilled). Do not modify.
__launch_bounds__(256, 4)
__global__ void k_mlp(const float* __restrict__ ws,
                      const float* __restrict__ W1, const float* __restrict__ b1,
                      const float* __restrict__ Wf1, const float* __restrict__ bf1,
                      const float* __restrict__ b2, const float* __restrict__ bf2,
                      float* __restrict__ contrib) {
    __shared__ unsigned short sW2[4096], sWf2[4096];
    __shared__ unsigned short sW3E[11*520];   // r-stride 520 (pad 8)
    __shared__ float sB3E[11*12];
    __shared__ float sBB[220];
    int tid = threadIdx.x;
    int t = blockIdx.x & 63;
    {
        const unsigned* g2  = (const unsigned*)((const unsigned short*)(ws + OFF_W2A)  + t*4096);
        const unsigned* g2f = (const unsigned*)((const unsigned short*)(ws + OFF_WF2A) + t*4096);
        unsigned* s2  = (unsigned*)sW2;
        unsigned* s2f = (unsigned*)sWf2;
        #pragma unroll
        for (int i = 0; i < 8; ++i) {
            s2[i*256 + tid]  = g2[i*256 + tid];
            s2f[i*256 + tid] = g2f[i*256 + tid];
        }
        const unsigned* g3 = (const unsigned*)((const unsigned short*)(ws + OFF_W3EB) + (size_t)t*5632);
        unsigned* s3 = (unsigned*)sW3E;
        for (int i = tid; i < 2816; i += 256) {
            int r = i >> 8, off = i & 255;
            s3[r*260 + off] = g3[i];
        }
        if (tid < 88) {
            int r = tid >> 3, o = tid & 7;
            sB3E[r*12 + o] = ws[OFF_B3E + t*88 + tid];
        }
        if (tid < 220) sBB[tid] = ws[OFF_BB + t*220 + tid];
    }
    __syncthreads();
    int L = tid & 63, l15 = L & 15, q4 = L >> 4;
    int pbase = (blockIdx.x >> 6) * 256 + (tid >> 6) * 64;

    float4 bh4[4], bf4[4];
    #pragma unroll
    for (int ct = 0; ct < 4; ++ct) {
        bh4[ct] = *(const float4*)(b2  + t*64 + ct*16 + q4*4);
        bf4[ct] = *(const float4*)(bf2 + t*64 + ct*16 + q4*4);
    }
    const float* GEO = ws + OFF_GEO;
    const float* SM  = ws + OFF_SM;
    const float* W1t  = W1  + t*384;
    const float* Wf1t = Wf1 + t*384;
    const float* b1t  = b1  + t*64;
    const float* bf1t = bf1 + t*64;

    // prefetch g=0
    int base_n = t*BATCH + pbase + l15;
    float2 sm_n = *(const float2*)(SM + (size_t)base_n*2);
    float4 ga_n = *(const float4*)(GEO + (size_t)base_n*12);
    float4 gb_n = *(const float4*)(GEO + (size_t)base_n*12 + 4);
    float4 gc_n = *(const float4*)(GEO + (size_t)base_n*12 + 8);

    #pragma unroll 1
    for (int g = 0; g < 4; ++g) {
        int base = base_n;
        float2 sm = sm_n;
        float4 ga = ga_n, gb = gb_n, gc = gc_n;
        if (g < 3) {
            base_n = t*BATCH + pbase + (g+1)*16 + l15;
            sm_n = *(const float2*)(SM + (size_t)base_n*2);
            ga_n = *(const float4*)(GEO + (size_t)base_n*12);
            gb_n = *(const float4*)(GEO + (size_t)base_n*12 + 4);
            gc_n = *(const float4*)(GEO + (size_t)base_n*12 + 8);
        }
        float scale = sm.x;
        if (__ballot(scale != 0.f) == 0ULL) {
            if (q4 == 0) contrib[base] = 0.f;
            continue;
        }
        int meta = __float_as_int(sm.y);
        float inp[6]  = {ga.x, ga.y, ga.z, ga.w, gb.x, gb.y};
        float coef[6] = {gb.z, gb.w, gc.x, gc.y, gc.z, gc.w};
        int r = meta & 255, sa = (meta >> 8) & 255;
        bool jump = ((meta >> 16) & 1) != 0;

        // L1 -> B-fragments (B[k=q4*8+j][n=l15])
        short8 bh[2], bfr[2];
        #pragma unroll
        for (int kt = 0; kt < 2; ++kt) {
            int kb = kt*32 + q4*8;
            float av[8], fv[8];
            #pragma unroll
            for (int j = 0; j < 8; ++j) { av[j] = b1t[kb+j]; fv[j] = bf1t[kb+j]; }
            #pragma unroll
            for (int i = 0; i < 6; ++i) {
                float x = inp[i];
                #pragma unroll
                for (int j = 0; j < 8; ++j) {
                    av[j] = fmaf(x, W1t[i*64 + kb + j],  av[j]);
                    fv[j] = fmaf(x, Wf1t[i*64 + kb + j], fv[j]);
                }
            }
            short8 vh, vf;
            unsigned* vhp = (unsigned*)&vh;
            unsigned* vfp = (unsigned*)&vf;
            #pragma unroll
            for (int j = 0; j < 4; ++j) {
                vhp[j] = cvt_pk_bf16(tanh_f(av[2*j]), tanh_f(av[2*j+1]));
                vfp[j] = cvt_pk_bf16(tanh_f(fv[2*j]), tanh_f(fv[2*j+1]));
            }
            bh[kt] = vh; bfr[kt] = vf;
        }

        const unsigned short* W3E8 = sW3E + r*520;
        const float* btp = ws + OFF_BT + ((size_t)(t*11 + r)*20 + sa)*64;
        float pdp = 0.f;
        #pragma unroll
        for (int ct = 0; ct < 4; ++ct) {
            short8 a0 = *(const short8*)(sW2  + ((ct*2 + 0)*64 + L)*8);
            short8 a1 = *(const short8*)(sW2  + ((ct*2 + 1)*64 + L)*8);
            short8 c0 = *(const short8*)(sWf2 + ((ct*2 + 0)*64 + L)*8);
            short8 c1 = *(const short8*)(sWf2 + ((ct*2 + 1)*64 + L)*8);
            // bias as MFMA C-init (D = A*B + C): kills the post-MFMA adds
            f32x4 acc  = {bh4[ct].x, bh4[ct].y, bh4[ct].z, bh4[ct].w};
            f32x4 accf = {bf4[ct].x, bf4[ct].y, bf4[ct].z, bf4[ct].w};
            acc  = __builtin_amdgcn_mfma_f32_16x16x32_bf16(a0, bh[0],  acc,  0, 0, 0);
            acc  = __builtin_amdgcn_mfma_f32_16x16x32_bf16(a1, bh[1],  acc,  0, 0, 0);
            accf = __builtin_amdgcn_mfma_f32_16x16x32_bf16(c0, bfr[0], accf, 0, 0, 0);
            accf = __builtin_amdgcn_mfma_f32_16x16x32_bf16(c1, bfr[1], accf, 0, 0, 0);
            #pragma unroll
            for (int reg = 0; reg < 4; ++reg) {
                float h2 = tanh_f(acc[reg]);
                float f2 = tanh_f(accf[reg]);
                int c = ct*16 + q4*4 + reg;
                short8 wv = *(const short8*)(W3E8 + c*8);
                float s = bf16f((unsigned short)wv[0])*coef[0]
                        + bf16f((unsigned short)wv[1])*coef[1]
                        + bf16f((unsigned short)wv[2])*coef[2]
                        + bf16f((unsigned short)wv[3])*coef[3]
                        + bf16f((unsigned short)wv[4])*coef[4]
                        + bf16f((unsigned short)wv[5])*coef[5];
                pdp = fmaf(h2, s, pdp);
                pdp = fmaf(f2, bf16f((unsigned short)wv[6]), pdp);   // CT, -DT pre-folded
                if (jump) pdp = fmaf(f2, btp[c], pdp);
            }
        }
        pdp += __shfl_xor(pdp, 16, 64);
        pdp += __shfl_xor(pdp, 32, 64);

        const float* B3E8 = sB3E + r*12;
        float4 ba  = *(const float4*)(B3E8);
        float4 bbv = *(const float4*)(B3E8 + 4);
        float dpart = pdp
            + ba.x*coef[0] + ba.y*coef[1] + ba.z*coef[2]
            + ba.w*coef[3] + bbv.x*coef[4] + bbv.y*coef[5]
            + bbv.z;                                   // BC, -DT pre-folded
        if (jump) dpart += sBB[r*20 + sa];
        if (q4 == 0) contrib[base] = scale * dpart;
    }
}

// =========== K6: reduce over t ============================================
__global__ void k_reduce(const float* __restrict__ contrib, const float* __restrict__ u,
                         float* out) {
    __shared__ float red[256];
    int tid = threadIdx.x;
    int pi = tid & 31, tc = tid >> 5;
    int p = blockIdx.x * 32 + pi;
    float a = 0.f;
    #pragma unroll
    for (int j = 0; j < 8; ++j) a += contrib[(tc*8 + j)*BATCH + p];
    red[tid] = a;
    __syncthreads();
    if (tid < 32) {
        float s = u[0];
        #pragma unroll
        for (int c = 0; c < 8; ++c) s += red[c*32 + pi];
        out[p] = s;
    }
}

extern "C" void kernel_launch(void* const* d_in, const int* in_sizes, int n_in,
                              void* d_out, int out_size, void* d_ws, size_t ws_size,
                              hipStream_t stream) {
    const float* u      = (const float*)d_in[0];
    const float* jump_r = (const float*)d_in[1];
    const float* jump_l = (const float*)d_in[2];
    const float* W1  = (const float*)d_in[3];
    const float* b1  = (const float*)d_in[4];
    const float* W2  = (const float*)d_in[5];
    const float* b2  = (const float*)d_in[6];
    const float* W3  = (const float*)d_in[7];
    const float* b3  = (const float*)d_in[8];
    const float* emb = (const float*)d_in[9];
    const float* Wf1 = (const float*)d_in[10];
    const float* bf1 = (const float*)d_in[11];
    const float* Wf2 = (const float*)d_in[12];
    const float* bf2 = (const float*)d_in[13];
    const float* Wf3 = (const float*)d_in[14];
    const float* bf3 = (const float*)d_in[15];
    const int*   rt0 = (const int*)d_in[16];
    const float* xt0 = (const float*)d_in[17];
    const float* yt0 = (const float*)d_in[18];
    const float* dBx = (const float*)d_in[19];
    const float* dBy = (const float*)d_in[20];
    const float* junif = (const float*)d_in[21];
    const float* sunif = (const float*)d_in[22];
    const float* mcu = (const float*)d_in[23];
    const float* jm  = (const float*)d_in[24];
    const float* cr  = (const float*)d_in[25];
    const float* cfr = (const float*)d_in[26];
    float* ws  = (float*)d_ws;
    float* out = (float*)d_out;

    hipMemsetAsync(ws + OFF_HIST, 0, 220*sizeof(int), stream);
    k_prep<<<4460, 256, 0, stream>>>(rt0, xt0, yt0, dBx, dBy, junif, sunif,
                                     jm, cr, cfr, mcu, W2, Wf2,
                                     W3, b3, emb, Wf3, bf3, jump_r, jump_l,
                                     ws, (int*)(ws + OFF_HIST), out);
    k_fold<<<64, 256, 0, stream>>>((const int*)(ws + OFF_HIST), cr, ws);
    k_mlp<<<2048, 256, 0, stream>>>(ws, W1, b1, Wf1, bf1, b2, bf2,
                                    ws + OFF_CONTRIB);
    k_reduce<<<256, 256, 0, stream>>>(ws + OFF_CONTRIB, u, out);
}

// Round 14
// 283.263 us; speedup vs baseline: 1.2020x; 1.0091x over previous
//
#include <hip/hip_runtime.h>
#include <math.h>

#define NUMR 11
#define NSTEP 64
#define BATCH 8192
#define PDIM 128
#define MC 10000
#define DT (1.0f/64.0f)
#define RDOM 5.0f
#define CAP_EPS 0.1f
#define TP (NSTEP*BATCH)        // 524288

// workspace float offsets
#define OFF_HIST 0              // 220 ints
#define OFF_W3EB 256            // bf16 [t][r][c][8]: o0..5, CT(-DT folded), pad
#define OFF_B3E  180480         // f32 [t][r][8]: o0..5, BC(-DT folded), pad
#define OFF_BT   186112         // f32 [t][r][sa][c]
#define OFF_BB   1087232        // f32 [t][r][sa]
#define OFF_W2A  1101312        // bf16 A-ordered [t][4096]
#define OFF_WF2A 1232384
#define OFF_GEO  1363456        // f32 [t][p][12]
#define OFF_SM   7654912        // f32 [t][p][2] {scale, meta}
#define OFF_CONTRIB 8703488     // f32 [t][p]

typedef __attribute__((ext_vector_type(8))) short short8;   // 8 bf16
typedef __attribute__((ext_vector_type(4))) float f32x4;

// tanh via native exp2: exp(2x) = 2^(x*2log2e) — folds the *2 into the
// exp constant (one v_mul fewer per tanh; 64 tanh/lane/g in k_mlp).
__device__ __forceinline__ float tanh_f(float x) {
    float e = __builtin_amdgcn_exp2f(x * 2.885390082f);
    return 1.0f - 2.0f * __builtin_amdgcn_rcpf(e + 1.0f);
}
__device__ __forceinline__ unsigned short bf16bits(float f) {
    unsigned u = __float_as_uint(f);
    return (unsigned short)((u + 0x7FFFu + ((u >> 16) & 1u)) >> 16);
}
__device__ __forceinline__ float bf16f(unsigned short s) {
    return __uint_as_float(((unsigned)s) << 16);
}
// HW packed f32->bf16 (RNE, matches bf16bits on normals; no builtin on gfx950)
__device__ __forceinline__ unsigned cvt_pk_bf16(float lo, float hi) {
    unsigned r;
    asm("v_cvt_pk_bf16_f32 %0, %1, %2" : "=v"(r) : "v"(lo), "v"(hi));
    return r;
}

__device__ __forceinline__ void reflect3(float* p, float* g) {
    float nr = sqrtf(p[0]*p[0] + p[1]*p[1] + p[2]*p[2]);
    if (nr > RDOM) {
        float inv = 1.0f / fmaxf(nr, 1e-12f);   // exact div: trajectory-sensitive
        float nb0 = p[0]*inv, nb1 = p[1]*inv, nb2 = p[2]*inv;
        float sc = 2.0f*RDOM - nr;
        p[0] = nb0*sc; p[1] = nb1*sc; p[2] = nb2*sc;
        #pragma unroll
        for (int j = 0; j < 3; ++j) {
            float proj = nb0*g[j] + nb1*g[3+j] + nb2*g[6+j];
            g[j]   -= 2.0f*nb0*proj;
            g[3+j] -= 2.0f*nb1*proj;
            g[6+j] -= 2.0f*nb2*proj;
        }
    }
}

// =========== K_A: fused prep ==============================================
// [0,128): geom | [128,236): hist | [236,300): pack | [300,4460): tables.
// Geom: 2-step-deep input prefetch (per-step compute ~600cy < HBM ~900cy).
// Tables branch LDS-stages all dot-product inputs; strides padded to 132.
__launch_bounds__(256)
__global__ void k_prep(const int* __restrict__ rt0, const float* __restrict__ xt0,
                       const float* __restrict__ yt0, const float* __restrict__ dBx,
                       const float* __restrict__ dBy, const float* __restrict__ junif,
                       const float* __restrict__ sunif, const float* __restrict__ jm,
                       const float* __restrict__ cr, const float* __restrict__ cfr,
                       const float* __restrict__ mcu,
                       const float* __restrict__ W2, const float* __restrict__ Wf2,
                       const float* __restrict__ W3, const float* __restrict__ b3,
                       const float* __restrict__ emb, const float* __restrict__ Wf3,
                       const float* __restrict__ bf3, const float* __restrict__ jump_r,
                       const float* __restrict__ jump_l,
                       float* ws, int* hist, float* out) {
    // overlaid LDS: tables use 6440 floats; geom uses 242; hist uses 220 ints
    __shared__ float smem[6440];
    int blk = blockIdx.x, tid = threadIdx.x;

    if (blk < 128) {
        // ---------------- geom: 1 particle/thread, 64 working lanes -------
        float* sjm = smem; float* scr = smem + 220; float* smul = smem + 231;
        for (int i = tid; i < 220; i += 256) sjm[i] = jm[i];
        if (tid < 11) { scr[tid] = cr[tid]; smul[tid] = __expf(-cfr[tid]*DT); }
        __syncthreads();
        if (tid >= 64) return;
        int p = blk * 64 + tid;

        int rt = rt0[p];
        float xt[3], xin[3], yin[3], gtx[9], gty[9];
        #pragma unroll
        for (int i = 0; i < 3; ++i) { xt[i] = xt0[p*3+i]; xin[i] = xt[i]; yin[i] = yt0[p*3+i]; }
        #pragma unroll
        for (int i = 0; i < 9; ++i) { gtx[i] = (i % 4 == 0) ? 1.f : 0.f; gty[i] = gtx[i]; }
        float ef = 1.f, run = 1.f;

        // cur = t=0, nxt = t=1 (prefetched); loop issues t+2 at top of t
        float ju = junif[p], su = sunif[p];
        float dbx0 = dBx[(size_t)p*2], dbx1 = dBx[(size_t)p*2+1];
        float dby0 = dBy[(size_t)p*3], dby1 = dBy[(size_t)p*3+1], dby2 = dBy[(size_t)p*3+2];
        float nju=0.f,nsu=0.f,ndbx0=0.f,ndbx1=0.f,ndby0=0.f,ndby1=0.f,ndby2=0.f;
        {
            int nb = BATCH + p;
            nju = junif[nb]; nsu = sunif[nb];
            ndbx0 = dBx[(size_t)nb*2]; ndbx1 = dBx[(size_t)nb*2+1];
            ndby0 = dBy[(size_t)nb*3]; ndby1 = dBy[(size_t)nb*3+1]; ndby2 = dBy[(size_t)nb*3+2];
        }

        float* GEO = ws + OFF_GEO;
        float* SM  = ws + OFF_SM;
        #pragma unroll 1
        for (int t = 0; t < NSTEP; ++t) {
            float mju=0.f,msu=0.f,mdbx0=0.f,mdbx1=0.f,mdby0=0.f,mdby1=0.f,mdby2=0.f;
            if (t < NSTEP-2) {
                int nb = (t+2)*BATCH + p;
                mju = junif[nb]; msu = sunif[nb];
                mdbx0 = dBx[(size_t)nb*2]; mdbx1 = dBx[(size_t)nb*2+1];
                mdby0 = dBy[(size_t)nb*3]; mdby1 = dBy[(size_t)nb*3+1]; mdby2 = dBy[(size_t)nb*3+2];
            }
            int base = t*BATCH + p;
            int r = rt - 10;
            int jon = (ju < scr[r]*DT) ? 1 : 0;
            int cnt = 0;
            #pragma unroll
            for (int j = 0; j < 20; ++j) cnt += (su < sjm[r*20+j]) ? 1 : 0;
            int ind = 20 - cnt;
            int drt = (ind < 10) ? (ind+1) : -(ind-9);
            drt = jon ? drt : 0;
            int sa = (drt > 0) ? (drt-1) : ((drt < 0) ? (9-drt) : 0);
            int jf = (drt != 0) ? 1 : 0;

            float nx = fmaxf(sqrtf(xt[0]*xt[0]+xt[1]*xt[1]+xt[2]*xt[2]), 1e-12f);
            float c = fminf(1.f, fmaxf(-1.f, xt[2]/nx));
            float ct = sqrtf(fmaxf(0.f, 1.f - c*c));
            float st = -c;
            float rxy2 = xt[0]*xt[0] + xt[1]*xt[1];
            float cp = 1.f, sp = 0.f;
            if (rxy2 > 0.f) { float ir = 1.0f/sqrtf(rxy2); cp = xt[0]*ir; sp = xt[1]*ir; }
            float Ti[9];
            Ti[0]=cp*ct; Ti[1]=-sp; Ti[2]=cp*st;
            Ti[3]=sp*ct; Ti[4]=cp;  Ti[5]=sp*st;
            Ti[6]=-st;   Ti[7]=0.f; Ti[8]=ct;

            float sdx = 1.0f/(float)(r+10);
            float scale = run * ef;

            float cx[3], cy[3];
            #pragma unroll
            for (int i = 0; i < 3; ++i) {
                float w31 = gtx[i*3]*Ti[1] + gtx[i*3+1]*Ti[4] + gtx[i*3+2]*Ti[7];
                float w32 = gtx[i*3]*Ti[2] + gtx[i*3+1]*Ti[5] + gtx[i*3+2]*Ti[8];
                cx[i] = sdx * (w31*dbx1 - w32*dbx0);
                cy[i] = gty[i*3]*dby0 + gty[i*3+1]*dby1 + gty[i*3+2]*dby2;
            }
            float* gp = GEO + (size_t)base*12;
            float4 v0 = {xin[0], xin[1], xin[2], yin[0]};
            float4 v1 = {yin[1], yin[2], cx[0], cx[1]};
            float4 v2 = {cx[2], cy[0], cy[1], cy[2]};
            *(float4*)(gp)     = v0;
            *(float4*)(gp + 4) = v1;
            *(float4*)(gp + 8) = v2;
            float2 smv = {scale, __int_as_float(r | (sa<<8) | (jf<<16))};
            *(float2*)(SM + (size_t)base*2) = smv;

            ef *= smul[r];

            // Taylor sin/cos: |dX| <= ~0.075, err ~8e-9
            float dX0 = sdx*dbx0, dX1 = sdx*dbx1;
            float x2 = dX0*dX0, y2 = dX1*dX1;
            float s0 = dX0*(1.f - x2*(1.f/6.f));
            float cc0 = 1.f - x2*0.5f + x2*x2*(1.f/24.f);
            float s1 = dX1*(1.f - y2*(1.f/6.f));
            float cc1 = 1.f - y2*0.5f + y2*y2*(1.f/24.f);
            float cart0 = cc0*cc1 - 1.0f, cart1 = cc0*s1, cart2 = -s0;
            float dX3[3];
            #pragma unroll
            for (int i = 0; i < 3; ++i)
                dX3[i] = Ti[i*3]*cart0 + Ti[i*3+1]*cart1 + Ti[i*3+2]*cart2;
            #pragma unroll
            for (int i = 0; i < 3; ++i) xt[i] += dX3[i];
            #pragma unroll
            for (int i = 0; i < 3; ++i)
                xin[i] += gtx[i*3]*dX3[0] + gtx[i*3+1]*dX3[1] + gtx[i*3+2]*dX3[2];
            #pragma unroll
            for (int i = 0; i < 3; ++i)
                yin[i] += gty[i*3]*dby0 + gty[i*3+1]*dby1 + gty[i*3+2]*dby2;
            rt += drt; rt = (rt < 10) ? 10 : ((rt > 20) ? 20 : rt);
            reflect3(xin, gtx);
            reflect3(yin, gty);
            float d0 = xin[0]-yin[0], d1 = xin[1]-yin[1], d2 = xin[2]-yin[2];
            if (sqrtf(d0*d0 + d1*d1 + d2*d2) < CAP_EPS) run = 0.f;

            ju = nju; su = nsu; dbx0 = ndbx0; dbx1 = ndbx1;
            dby0 = ndby0; dby1 = ndby1; dby2 = ndby2;
            nju = mju; nsu = msu; ndbx0 = mdbx0; ndbx1 = mdbx1;
            ndby0 = mdby0; ndby1 = mdby1; ndby2 = mdby2;
        }
        float d0 = xin[0]-yin[0], d1 = xin[1]-yin[1], d2 = xin[2]-yin[2];
        float u0v = __expf(-(d0*d0 + d1*d1 + d2*d2));
        out[BATCH + p] = run * u0v * ef;

    } else if (blk < 236) {
        // ---------------- hist ----------------
        int* lh = (int*)smem;
        for (int i = tid; i < 220; i += 256) lh[i] = 0;
        __syncthreads();
        int hb = blk - 128;
        #pragma unroll
        for (int j = 0; j < 4; ++j) {
            int i = hb*1024 + j*256 + tid;
            if (i < MC*NUMR) {
                int r = i % NUMR;
                float u = mcu[i];
                int cnt = 0;
                #pragma unroll
                for (int k = 0; k < 20; ++k) cnt += (u < jm[r*20+k]) ? 1 : 0;
                int ind = 20 - cnt;
                int s = (ind < 10) ? (ind+1) : -(ind-9);
                int sa = (s > 0) ? (s-1) : (10 + (-s-1));
                atomicAdd(&lh[r*20+sa], 1);
            }
        }
        __syncthreads();
        if (tid < 220 && lh[tid]) atomicAdd(&hist[tid], lh[tid]);

    } else if (blk < 300) {
        // ---------------- pack W2/Wf2 -> bf16 MFMA-A-lane order -----------
        int t = blk - 236;
        unsigned short* W2A  = (unsigned short*)(ws + OFF_W2A)  + t*4096;
        unsigned short* WF2A = (unsigned short*)(ws + OFF_WF2A) + t*4096;
        for (int i = tid; i < 4096; i += 256) {
            int j = i & 7, L = (i >> 3) & 63, ktct = i >> 9;
            int ct = ktct >> 1, kt = ktct & 1;
            int c = ct*16 + (L & 15);
            int k = kt*32 + (L >> 4)*8 + j;
            W2A[i]  = bf16bits(W2[t*4096 + k*64 + c]);
            WF2A[i] = bf16bits(Wf2[t*4096 + k*64 + c]);
        }

    } else {
        // ---------------- tables (W3E slots 0-5 bf16, B3E, BT, BB) --------
        // LDS-staged inputs; identical FP order to the global-load version.
        int idx = blk - 300;
        int t = idx / 65, kk = idx % 65;
        bool brow = (kk == 64);
        const float* w3row = brow ? (b3 + t*768) : (W3 + (t*64+kk)*768);
        const float* wfrow = brow ? (bf3 + t*128) : (Wf3 + (t*64+kk)*128);
        unsigned short* W3EB = (unsigned short*)(ws + OFF_W3EB);

        float* sW3  = smem;          // 768
        float* sWf  = smem + 768;    // 128
        float* sEmb = smem + 896;    // 11*132 = 1452
        float* sJr  = smem + 2348;   // 11*132 = 1452
        float* sJl  = smem + 3800;   // 20*132 = 2640  (total 6440)
        for (int i = tid; i < 768; i += 256) sW3[i] = w3row[i];
        if (tid < 128) sWf[tid] = wfrow[tid];
        for (int i = tid; i < 1408; i += 256) {
            int r = i >> 7, p = i & 127;
            sEmb[r*132 + p] = emb[(t*11+r)*128 + p];
            sJr[r*132 + p]  = jump_r[i];
        }
        for (int i = tid; i < 2560; i += 256) {
            int sa = i >> 7, p = i & 127;
            sJl[sa*132 + p] = jump_l[i];
        }
        __syncthreads();

        for (int q = tid; q < 286; q += 256) {
            if (q < 66) {
                int o = q / 11, r = q % 11;
                const float* e = sEmb + r*132;
                float a0 = 0.f, a1 = 0.f;
                #pragma unroll 4
                for (int p = 0; p < 128; p += 2) {
                    a0 = fmaf(e[p],   sW3[p*6+o],     a0);
                    a1 = fmaf(e[p+1], sW3[(p+1)*6+o], a1);
                }
                float acc = a0 + a1;
                if (brow) ws[OFF_B3E + (t*11+r)*8 + o] = acc;
                else      W3EB[(size_t)((t*11+r)*64 + kk)*8 + o] = bf16bits(acc);
            } else {
                int qq = q - 66;
                int sa = qq / 11, r = qq % 11;
                const float* jr = sJr + r*132;
                const float* jl = sJl + sa*132;
                float a0 = 0.f, a1 = 0.f;
                #pragma unroll 4
                for (int p = 0; p < 128; p += 2) {
                    a0 = fmaf(sWf[p],   jr[p]   * jl[p],   a0);
                    a1 = fmaf(sWf[p+1], jr[p+1] * jl[p+1], a1);
                }
                float acc = a0 + a1;
                if (brow) ws[OFF_BB + (t*11+r)*20 + sa] = acc;
                else      ws[OFF_BT + ((size_t)(t*11+r)*20 + sa)*64 + kk] = acc;
            }
        }
    }
}

// =========== K_B: CT/BC from MC histogram; -DT folded into CT/BC ==========
__global__ void k_fold(const int* __restrict__ hist, const float* __restrict__ cr,
                       float* ws) {
    int t = blockIdx.x, tid = threadIdx.x;
    unsigned short* W3EB = (unsigned short*)(ws + OFF_W3EB);
    for (int i = tid; i < 715; i += 256) {
        if (i < 704) {
            int r = i >> 6, c = i & 63;
            float crn = cr[r] * (1.0f/(float)MC);
            const float* btp = ws + OFF_BT + (size_t)(t*11+r)*20*64 + c;
            float acc = 0.f;
            #pragma unroll
            for (int sa = 0; sa < 20; ++sa)
                acc += (float)hist[r*20+sa] * btp[sa*64];
            W3EB[(size_t)((t*11+r)*64 + c)*8 + 6] = bf16bits(acc * crn * (-DT));
        } else {
            int r = i - 704;
            float crn = cr[r] * (1.0f/(float)MC);
            float acc = 0.f;
            #pragma unroll
            for (int sa = 0; sa < 20; ++sa)
                acc += (float)hist[r*20+sa] * ws[OFF_BB + (t*11+r)*20 + sa];
            ws[OFF_B3E + (t*11+r)*8 + 6] = acc * crn * (-DT);
        }
    }
}

// =========== K5: MFMA MLP; W2 + r-tables in LDS; 4 blocks/CU ==============
// Round-10 body — session best. (256,4) + natural 64 VGPR is the verified
// sweet spot; body tolerates zero additional live state (r1/r2/r11 spilled).
// Only change this round: tanh_f uses exp2 with folded constant (global).
__launch_bounds__(256, 4)
__global__ void k_mlp(const float* __restrict__ ws,
                      const float* __restrict__ W1, const float* __restrict__ b1,
                      const float* __restrict__ Wf1, const float* __restrict__ bf1,
                      const float* __restrict__ b2, const float* __restrict__ bf2,
                      float* __restrict__ contrib) {
    __shared__ unsigned short sW2[4096], sWf2[4096];
    __shared__ unsigned short sW3E[11*520];   // r-stride 520 (pad 8)
    __shared__ float sB3E[11*12];
    __shared__ float sBB[220];
    int tid = threadIdx.x;
    int t = blockIdx.x & 63;
    {
        const unsigned* g2  = (const unsigned*)((const unsigned short*)(ws + OFF_W2A)  + t*4096);
        const unsigned* g2f = (const unsigned*)((const unsigned short*)(ws + OFF_WF2A) + t*4096);
        unsigned* s2  = (unsigned*)sW2;
        unsigned* s2f = (unsigned*)sWf2;
        #pragma unroll
        for (int i = 0; i < 8; ++i) {
            s2[i*256 + tid]  = g2[i*256 + tid];
            s2f[i*256 + tid] = g2f[i*256 + tid];
        }
        const unsigned* g3 = (const unsigned*)((const unsigned short*)(ws + OFF_W3EB) + (size_t)t*5632);
        unsigned* s3 = (unsigned*)sW3E;
        for (int i = tid; i < 2816; i += 256) {
            int r = i >> 8, off = i & 255;
            s3[r*260 + off] = g3[i];
        }
        if (tid < 88) {
            int r = tid >> 3, o = tid & 7;
            sB3E[r*12 + o] = ws[OFF_B3E + t*88 + tid];
        }
        if (tid < 220) sBB[tid] = ws[OFF_BB + t*220 + tid];
    }
    __syncthreads();
    int L = tid & 63, l15 = L & 15, q4 = L >> 4;
    int pbase = (blockIdx.x >> 6) * 256 + (tid >> 6) * 64;

    float4 bh4[4], bf4[4];
    #pragma unroll
    for (int ct = 0; ct < 4; ++ct) {
        bh4[ct] = *(const float4*)(b2  + t*64 + ct*16 + q4*4);
        bf4[ct] = *(const float4*)(bf2 + t*64 + ct*16 + q4*4);
    }
    const float* GEO = ws + OFF_GEO;
    const float* SM  = ws + OFF_SM;
    const float* W1t  = W1  + t*384;
    const float* Wf1t = Wf1 + t*384;
    const float* b1t  = b1  + t*64;
    const float* bf1t = bf1 + t*64;

    // prefetch g=0
    int base_n = t*BATCH + pbase + l15;
    float2 sm_n = *(const float2*)(SM + (size_t)base_n*2);
    float4 ga_n = *(const float4*)(GEO + (size_t)base_n*12);
    float4 gb_n = *(const float4*)(GEO + (size_t)base_n*12 + 4);
    float4 gc_n = *(const float4*)(GEO + (size_t)base_n*12 + 8);

    #pragma unroll 1
    for (int g = 0; g < 4; ++g) {
        int base = base_n;
        float2 sm = sm_n;
        float4 ga = ga_n, gb = gb_n, gc = gc_n;
        if (g < 3) {
            base_n = t*BATCH + pbase + (g+1)*16 + l15;
            sm_n = *(const float2*)(SM + (size_t)base_n*2);
            ga_n = *(const float4*)(GEO + (size_t)base_n*12);
            gb_n = *(const float4*)(GEO + (size_t)base_n*12 + 4);
            gc_n = *(const float4*)(GEO + (size_t)base_n*12 + 8);
        }
        float scale = sm.x;
        if (__ballot(scale != 0.f) == 0ULL) {
            if (q4 == 0) contrib[base] = 0.f;
            continue;
        }
        int meta = __float_as_int(sm.y);
        float inp[6]  = {ga.x, ga.y, ga.z, ga.w, gb.x, gb.y};
        float coef[6] = {gb.z, gb.w, gc.x, gc.y, gc.z, gc.w};
        int r = meta & 255, sa = (meta >> 8) & 255;
        bool jump = ((meta >> 16) & 1) != 0;

        // L1 -> B-fragments (B[k=q4*8+j][n=l15])
        short8 bh[2], bfr[2];
        #pragma unroll
        for (int kt = 0; kt < 2; ++kt) {
            int kb = kt*32 + q4*8;
            float av[8], fv[8];
            #pragma unroll
            for (int j = 0; j < 8; ++j) { av[j] = b1t[kb+j]; fv[j] = bf1t[kb+j]; }
            #pragma unroll
            for (int i = 0; i < 6; ++i) {
                float x = inp[i];
                #pragma unroll
                for (int j = 0; j < 8; ++j) {
                    av[j] = fmaf(x, W1t[i*64 + kb + j],  av[j]);
                    fv[j] = fmaf(x, Wf1t[i*64 + kb + j], fv[j]);
                }
            }
            short8 vh, vf;
            unsigned* vhp = (unsigned*)&vh;
            unsigned* vfp = (unsigned*)&vf;
            #pragma unroll
            for (int j = 0; j < 4; ++j) {
                vhp[j] = cvt_pk_bf16(tanh_f(av[2*j]), tanh_f(av[2*j+1]));
                vfp[j] = cvt_pk_bf16(tanh_f(fv[2*j]), tanh_f(fv[2*j+1]));
            }
            bh[kt] = vh; bfr[kt] = vf;
        }

        const unsigned short* W3E8 = sW3E + r*520;
        const float* btp = ws + OFF_BT + ((size_t)(t*11 + r)*20 + sa)*64;
        float pdp = 0.f;
        #pragma unroll
        for (int ct = 0; ct < 4; ++ct) {
            short8 a0 = *(const short8*)(sW2  + ((ct*2 + 0)*64 + L)*8);
            short8 a1 = *(const short8*)(sW2  + ((ct*2 + 1)*64 + L)*8);
            short8 c0 = *(const short8*)(sWf2 + ((ct*2 + 0)*64 + L)*8);
            short8 c1 = *(const short8*)(sWf2 + ((ct*2 + 1)*64 + L)*8);
            // bias as MFMA C-init (D = A*B + C): kills the post-MFMA adds
            f32x4 acc  = {bh4[ct].x, bh4[ct].y, bh4[ct].z, bh4[ct].w};
            f32x4 accf = {bf4[ct].x, bf4[ct].y, bf4[ct].z, bf4[ct].w};
            acc  = __builtin_amdgcn_mfma_f32_16x16x32_bf16(a0, bh[0],  acc,  0, 0, 0);
            acc  = __builtin_amdgcn_mfma_f32_16x16x32_bf16(a1, bh[1],  acc,  0, 0, 0);
            accf = __builtin_amdgcn_mfma_f32_16x16x32_bf16(c0, bfr[0], accf, 0, 0, 0);
            accf = __builtin_amdgcn_mfma_f32_16x16x32_bf16(c1, bfr[1], accf, 0, 0, 0);
            #pragma unroll
            for (int reg = 0; reg < 4; ++reg) {
                float h2 = tanh_f(acc[reg]);
                float f2 = tanh_f(accf[reg]);
                int c = ct*16 + q4*4 + reg;
                short8 wv = *(const short8*)(W3E8 + c*8);
                float s = bf16f((unsigned short)wv[0])*coef[0]
                        + bf16f((unsigned short)wv[1])*coef[1]
                        + bf16f((unsigned short)wv[2])*coef[2]
                        + bf16f((unsigned short)wv[3])*coef[3]
                        + bf16f((unsigned short)wv[4])*coef[4]
                        + bf16f((unsigned short)wv[5])*coef[5];
                pdp = fmaf(h2, s, pdp);
                pdp = fmaf(f2, bf16f((unsigned short)wv[6]), pdp);   // CT, -DT pre-folded
                if (jump) pdp = fmaf(f2, btp[c], pdp);
            }
        }
        pdp += __shfl_xor(pdp, 16, 64);
        pdp += __shfl_xor(pdp, 32, 64);

        const float* B3E8 = sB3E + r*12;
        float4 ba  = *(const float4*)(B3E8);
        float4 bbv = *(const float4*)(B3E8 + 4);
        float dpart = pdp
            + ba.x*coef[0] + ba.y*coef[1] + ba.z*coef[2]
            + ba.w*coef[3] + bbv.x*coef[4] + bbv.y*coef[5]
            + bbv.z;                                   // BC, -DT pre-folded
        if (jump) dpart += sBB[r*20 + sa];
        if (q4 == 0) contrib[base] = scale * dpart;
    }
}

// =========== K6: reduce over t ============================================
__global__ void k_reduce(const float* __restrict__ contrib, const float* __restrict__ u,
                         float* out) {
    __shared__ float red[256];
    int tid = threadIdx.x;
    int pi = tid & 31, tc = tid >> 5;
    int p = blockIdx.x * 32 + pi;
    float a = 0.f;
    #pragma unroll
    for (int j = 0; j < 8; ++j) a += contrib[(tc*8 + j)*BATCH + p];
    red[tid] = a;
    __syncthreads();
    if (tid < 32) {
        float s = u[0];
        #pragma unroll
        for (int c = 0; c < 8; ++c) s += red[c*32 + pi];
        out[p] = s;
    }
}

extern "C" void kernel_launch(void* const* d_in, const int* in_sizes, int n_in,
                              void* d_out, int out_size, void* d_ws, size_t ws_size,
                              hipStream_t stream) {
    const float* u      = (const float*)d_in[0];
    const float* jump_r = (const float*)d_in[1];
    const float* jump_l = (const float*)d_in[2];
    const float* W1  = (const float*)d_in[3];
    const float* b1  = (const float*)d_in[4];
    const float* W2  = (const float*)d_in[5];
    const float* b2  = (const float*)d_in[6];
    const float* W3  = (const float*)d_in[7];
    const float* b3  = (const float*)d_in[8];
    const float* emb = (const float*)d_in[9];
    const float* Wf1 = (const float*)d_in[10];
    const float* bf1 = (const float*)d_in[11];
    const float* Wf2 = (const float*)d_in[12];
    const float* bf2 = (const float*)d_in[13];
    const float* Wf3 = (const float*)d_in[14];
    const float* bf3 = (const float*)d_in[15];
    const int*   rt0 = (const int*)d_in[16];
    const float* xt0 = (const float*)d_in[17];
    const float* yt0 = (const float*)d_in[18];
    const float* dBx = (const float*)d_in[19];
    const float* dBy = (const float*)d_in[20];
    const float* junif = (const float*)d_in[21];
    const float* sunif = (const float*)d_in[22];
    const float* mcu = (const float*)d_in[23];
    const float* jm  = (const float*)d_in[24];
    const float* cr  = (const float*)d_in[25];
    const float* cfr = (const float*)d_in[26];
    float* ws  = (float*)d_ws;
    float* out = (float*)d_out;

    hipMemsetAsync(ws + OFF_HIST, 0, 220*sizeof(int), stream);
    k_prep<<<4460, 256, 0, stream>>>(rt0, xt0, yt0, dBx, dBy, junif, sunif,
                                     jm, cr, cfr, mcu, W2, Wf2,
                                     W3, b3, emb, Wf3, bf3, jump_r, jump_l,
                                     ws, (int*)(ws + OFF_HIST), out);
    k_fold<<<64, 256, 0, stream>>>((const int*)(ws + OFF_HIST), cr, ws);
    k_mlp<<<2048, 256, 0, stream>>>(ws, W1, b1, Wf1, bf1, b2, bf2,
                                    ws + OFF_CONTRIB);
    k_reduce<<<256, 256, 0, stream>>>(ws + OFF_CONTRIB, u, out);
}

// Round 15
// 260.948 us; speedup vs baseline: 1.3048x; 1.0855x over previous
//
#include <hip/hip_runtime.h>
#include <math.h>

#define NUMR 11
#define NSTEP 64
#define BATCH 8192
#define PDIM 128
#define MC 10000
#define DT (1.0f/64.0f)
#define RDOM 5.0f
#define CAP_EPS 0.1f
#define TP (NSTEP*BATCH)        // 524288

// workspace float offsets
#define OFF_HIST 0              // 220 ints
#define OFF_W3EB 256            // bf16 [t][r][c][8]: o0..5, CT(-DT folded), pad
#define OFF_B3E  180480         // f32 [t][r][8]: o0..5, BC(-DT folded), pad
#define OFF_BT   186112         // f32 [t][r][sa][c]
#define OFF_BB   1087232        // f32 [t][r][sa]
#define OFF_W2A  1101312        // bf16 A-ordered [t][4096]
#define OFF_WF2A 1232384
#define OFF_GEO  1363456        // f32 [t][p][12]
#define OFF_SM   7654912        // f32 [t][p][2] {scale, meta}
#define OFF_CONTRIB 8703488     // f32 [t][p]

typedef __attribute__((ext_vector_type(8))) short short8;   // 8 bf16
typedef __attribute__((ext_vector_type(4))) float f32x4;

// tanh via native exp2: exp(2x) = 2^(x*2log2e) — folds the *2 into the
// exp constant (one v_mul fewer per tanh; 64 tanh/lane/g in k_mlp).
__device__ __forceinline__ float tanh_f(float x) {
    float e = __builtin_amdgcn_exp2f(x * 2.885390082f);
    return 1.0f - 2.0f * __builtin_amdgcn_rcpf(e + 1.0f);
}
__device__ __forceinline__ unsigned short bf16bits(float f) {
    unsigned u = __float_as_uint(f);
    return (unsigned short)((u + 0x7FFFu + ((u >> 16) & 1u)) >> 16);
}
__device__ __forceinline__ float bf16f(unsigned short s) {
    return __uint_as_float(((unsigned)s) << 16);
}
// HW packed f32->bf16 (RNE, matches bf16bits on normals; no builtin on gfx950)
__device__ __forceinline__ unsigned cvt_pk_bf16(float lo, float hi) {
    unsigned r;
    asm("v_cvt_pk_bf16_f32 %0, %1, %2" : "=v"(r) : "v"(lo), "v"(hi));
    return r;
}

__device__ __forceinline__ void reflect3(float* p, float* g) {
    float nr = sqrtf(p[0]*p[0] + p[1]*p[1] + p[2]*p[2]);
    if (nr > RDOM) {
        float inv = 1.0f / fmaxf(nr, 1e-12f);   // exact div: trajectory-sensitive
        float nb0 = p[0]*inv, nb1 = p[1]*inv, nb2 = p[2]*inv;
        float sc = 2.0f*RDOM - nr;
        p[0] = nb0*sc; p[1] = nb1*sc; p[2] = nb2*sc;
        #pragma unroll
        for (int j = 0; j < 3; ++j) {
            float proj = nb0*g[j] + nb1*g[3+j] + nb2*g[6+j];
            g[j]   -= 2.0f*nb0*proj;
            g[3+j] -= 2.0f*nb1*proj;
            g[6+j] -= 2.0f*nb2*proj;
        }
    }
}

// =========== K_A: fused prep ==============================================
// [0,128): geom | [128,236): hist | [236,300): pack | [300,4460): tables.
// Geom: 2-step-deep input prefetch (per-step compute ~600cy < HBM ~900cy).
// Tables branch LDS-stages all dot-product inputs; strides padded to 132.
__launch_bounds__(256)
__global__ void k_prep(const int* __restrict__ rt0, const float* __restrict__ xt0,
                       const float* __restrict__ yt0, const float* __restrict__ dBx,
                       const float* __restrict__ dBy, const float* __restrict__ junif,
                       const float* __restrict__ sunif, const float* __restrict__ jm,
                       const float* __restrict__ cr, const float* __restrict__ cfr,
                       const float* __restrict__ mcu,
                       const float* __restrict__ W2, const float* __restrict__ Wf2,
                       const float* __restrict__ W3, const float* __restrict__ b3,
                       const float* __restrict__ emb, const float* __restrict__ Wf3,
                       const float* __restrict__ bf3, const float* __restrict__ jump_r,
                       const float* __restrict__ jump_l,
                       float* ws, int* hist, float* out) {
    // overlaid LDS: tables use 6440 floats; geom uses 242; hist uses 220 ints
    __shared__ float smem[6440];
    int blk = blockIdx.x, tid = threadIdx.x;

    if (blk < 128) {
        // ---------------- geom: 1 particle/thread, 64 working lanes -------
        float* sjm = smem; float* scr = smem + 220; float* smul = smem + 231;
        for (int i = tid; i < 220; i += 256) sjm[i] = jm[i];
        if (tid < 11) { scr[tid] = cr[tid]; smul[tid] = __expf(-cfr[tid]*DT); }
        __syncthreads();
        if (tid >= 64) return;
        int p = blk * 64 + tid;

        int rt = rt0[p];
        float xt[3], xin[3], yin[3], gtx[9], gty[9];
        #pragma unroll
        for (int i = 0; i < 3; ++i) { xt[i] = xt0[p*3+i]; xin[i] = xt[i]; yin[i] = yt0[p*3+i]; }
        #pragma unroll
        for (int i = 0; i < 9; ++i) { gtx[i] = (i % 4 == 0) ? 1.f : 0.f; gty[i] = gtx[i]; }
        float ef = 1.f, run = 1.f;

        // cur = t=0, nxt = t=1 (prefetched); loop issues t+2 at top of t
        float ju = junif[p], su = sunif[p];
        float dbx0 = dBx[(size_t)p*2], dbx1 = dBx[(size_t)p*2+1];
        float dby0 = dBy[(size_t)p*3], dby1 = dBy[(size_t)p*3+1], dby2 = dBy[(size_t)p*3+2];
        float nju=0.f,nsu=0.f,ndbx0=0.f,ndbx1=0.f,ndby0=0.f,ndby1=0.f,ndby2=0.f;
        {
            int nb = BATCH + p;
            nju = junif[nb]; nsu = sunif[nb];
            ndbx0 = dBx[(size_t)nb*2]; ndbx1 = dBx[(size_t)nb*2+1];
            ndby0 = dBy[(size_t)nb*3]; ndby1 = dBy[(size_t)nb*3+1]; ndby2 = dBy[(size_t)nb*3+2];
        }

        float* GEO = ws + OFF_GEO;
        float* SM  = ws + OFF_SM;
        #pragma unroll 1
        for (int t = 0; t < NSTEP; ++t) {
            float mju=0.f,msu=0.f,mdbx0=0.f,mdbx1=0.f,mdby0=0.f,mdby1=0.f,mdby2=0.f;
            if (t < NSTEP-2) {
                int nb = (t+2)*BATCH + p;
                mju = junif[nb]; msu = sunif[nb];
                mdbx0 = dBx[(size_t)nb*2]; mdbx1 = dBx[(size_t)nb*2+1];
                mdby0 = dBy[(size_t)nb*3]; mdby1 = dBy[(size_t)nb*3+1]; mdby2 = dBy[(size_t)nb*3+2];
            }
            int base = t*BATCH + p;
            int r = rt - 10;
            int jon = (ju < scr[r]*DT) ? 1 : 0;
            int cnt = 0;
            #pragma unroll
            for (int j = 0; j < 20; ++j) cnt += (su < sjm[r*20+j]) ? 1 : 0;
            int ind = 20 - cnt;
            int drt = (ind < 10) ? (ind+1) : -(ind-9);
            drt = jon ? drt : 0;
            int sa = (drt > 0) ? (drt-1) : ((drt < 0) ? (9-drt) : 0);
            int jf = (drt != 0) ? 1 : 0;

            float nx = fmaxf(sqrtf(xt[0]*xt[0]+xt[1]*xt[1]+xt[2]*xt[2]), 1e-12f);
            float c = fminf(1.f, fmaxf(-1.f, xt[2]/nx));
            float ct = sqrtf(fmaxf(0.f, 1.f - c*c));
            float st = -c;
            float rxy2 = xt[0]*xt[0] + xt[1]*xt[1];
            float cp = 1.f, sp = 0.f;
            if (rxy2 > 0.f) { float ir = 1.0f/sqrtf(rxy2); cp = xt[0]*ir; sp = xt[1]*ir; }
            float Ti[9];
            Ti[0]=cp*ct; Ti[1]=-sp; Ti[2]=cp*st;
            Ti[3]=sp*ct; Ti[4]=cp;  Ti[5]=sp*st;
            Ti[6]=-st;   Ti[7]=0.f; Ti[8]=ct;

            float sdx = 1.0f/(float)(r+10);
            float scale = run * ef;

            float cx[3], cy[3];
            #pragma unroll
            for (int i = 0; i < 3; ++i) {
                float w31 = gtx[i*3]*Ti[1] + gtx[i*3+1]*Ti[4] + gtx[i*3+2]*Ti[7];
                float w32 = gtx[i*3]*Ti[2] + gtx[i*3+1]*Ti[5] + gtx[i*3+2]*Ti[8];
                cx[i] = sdx * (w31*dbx1 - w32*dbx0);
                cy[i] = gty[i*3]*dby0 + gty[i*3+1]*dby1 + gty[i*3+2]*dby2;
            }
            float* gp = GEO + (size_t)base*12;
            float4 v0 = {xin[0], xin[1], xin[2], yin[0]};
            float4 v1 = {yin[1], yin[2], cx[0], cx[1]};
            float4 v2 = {cx[2], cy[0], cy[1], cy[2]};
            *(float4*)(gp)     = v0;
            *(float4*)(gp + 4) = v1;
            *(float4*)(gp + 8) = v2;
            float2 smv = {scale, __int_as_float(r | (sa<<8) | (jf<<16))};
            *(float2*)(SM + (size_t)base*2) = smv;

            ef *= smul[r];

            // Taylor sin/cos: |dX| <= ~0.075, err ~8e-9
            float dX0 = sdx*dbx0, dX1 = sdx*dbx1;
            float x2 = dX0*dX0, y2 = dX1*dX1;
            float s0 = dX0*(1.f - x2*(1.f/6.f));
            float cc0 = 1.f - x2*0.5f + x2*x2*(1.f/24.f);
            float s1 = dX1*(1.f - y2*(1.f/6.f));
            float cc1 = 1.f - y2*0.5f + y2*y2*(1.f/24.f);
            float cart0 = cc0*cc1 - 1.0f, cart1 = cc0*s1, cart2 = -s0;
            float dX3[3];
            #pragma unroll
            for (int i = 0; i < 3; ++i)
                dX3[i] = Ti[i*3]*cart0 + Ti[i*3+1]*cart1 + Ti[i*3+2]*cart2;
            #pragma unroll
            for (int i = 0; i < 3; ++i) xt[i] += dX3[i];
            #pragma unroll
            for (int i = 0; i < 3; ++i)
                xin[i] += gtx[i*3]*dX3[0] + gtx[i*3+1]*dX3[1] + gtx[i*3+2]*dX3[2];
            #pragma unroll
            for (int i = 0; i < 3; ++i)
                yin[i] += gty[i*3]*dby0 + gty[i*3+1]*dby1 + gty[i*3+2]*dby2;
            rt += drt; rt = (rt < 10) ? 10 : ((rt > 20) ? 20 : rt);
            reflect3(xin, gtx);
            reflect3(yin, gty);
            float d0 = xin[0]-yin[0], d1 = xin[1]-yin[1], d2 = xin[2]-yin[2];
            if (sqrtf(d0*d0 + d1*d1 + d2*d2) < CAP_EPS) run = 0.f;

            ju = nju; su = nsu; dbx0 = ndbx0; dbx1 = ndbx1;
            dby0 = ndby0; dby1 = ndby1; dby2 = ndby2;
            nju = mju; nsu = msu; ndbx0 = mdbx0; ndbx1 = mdbx1;
            ndby0 = mdby0; ndby1 = mdby1; ndby2 = mdby2;
        }
        float d0 = xin[0]-yin[0], d1 = xin[1]-yin[1], d2 = xin[2]-yin[2];
        float u0v = __expf(-(d0*d0 + d1*d1 + d2*d2));
        out[BATCH + p] = run * u0v * ef;

    } else if (blk < 236) {
        // ---------------- hist ----------------
        int* lh = (int*)smem;
        for (int i = tid; i < 220; i += 256) lh[i] = 0;
        __syncthreads();
        int hb = blk - 128;
        #pragma unroll
        for (int j = 0; j < 4; ++j) {
            int i = hb*1024 + j*256 + tid;
            if (i < MC*NUMR) {
                int r = i % NUMR;
                float u = mcu[i];
                int cnt = 0;
                #pragma unroll
                for (int k = 0; k < 20; ++k) cnt += (u < jm[r*20+k]) ? 1 : 0;
                int ind = 20 - cnt;
                int s = (ind < 10) ? (ind+1) : -(ind-9);
                int sa = (s > 0) ? (s-1) : (10 + (-s-1));
                atomicAdd(&lh[r*20+sa], 1);
            }
        }
        __syncthreads();
        if (tid < 220 && lh[tid]) atomicAdd(&hist[tid], lh[tid]);

    } else if (blk < 300) {
        // ---------------- pack W2/Wf2 -> bf16 MFMA-A-lane order -----------
        int t = blk - 236;
        unsigned short* W2A  = (unsigned short*)(ws + OFF_W2A)  + t*4096;
        unsigned short* WF2A = (unsigned short*)(ws + OFF_WF2A) + t*4096;
        for (int i = tid; i < 4096; i += 256) {
            int j = i & 7, L = (i >> 3) & 63, ktct = i >> 9;
            int ct = ktct >> 1, kt = ktct & 1;
            int c = ct*16 + (L & 15);
            int k = kt*32 + (L >> 4)*8 + j;
            W2A[i]  = bf16bits(W2[t*4096 + k*64 + c]);
            WF2A[i] = bf16bits(Wf2[t*4096 + k*64 + c]);
        }

    } else {
        // ---------------- tables (W3E slots 0-5 bf16, B3E, BT, BB) --------
        // LDS-staged inputs; identical FP order to the global-load version.
        int idx = blk - 300;
        int t = idx / 65, kk = idx % 65;
        bool brow = (kk == 64);
        const float* w3row = brow ? (b3 + t*768) : (W3 + (t*64+kk)*768);
        const float* wfrow = brow ? (bf3 + t*128) : (Wf3 + (t*64+kk)*128);
        unsigned short* W3EB = (unsigned short*)(ws + OFF_W3EB);

        float* sW3  = smem;          // 768
        float* sWf  = smem + 768;    // 128
        float* sEmb = smem + 896;    // 11*132 = 1452
        float* sJr  = smem + 2348;   // 11*132 = 1452
        float* sJl  = smem + 3800;   // 20*132 = 2640  (total 6440)
        for (int i = tid; i < 768; i += 256) sW3[i] = w3row[i];
        if (tid < 128) sWf[tid] = wfrow[tid];
        for (int i = tid; i < 1408; i += 256) {
            int r = i >> 7, p = i & 127;
            sEmb[r*132 + p] = emb[(t*11+r)*128 + p];
            sJr[r*132 + p]  = jump_r[i];
        }
        for (int i = tid; i < 2560; i += 256) {
            int sa = i >> 7, p = i & 127;
            sJl[sa*132 + p] = jump_l[i];
        }
        __syncthreads();

        for (int q = tid; q < 286; q += 256) {
            if (q < 66) {
                int o = q / 11, r = q % 11;
                const float* e = sEmb + r*132;
                float a0 = 0.f, a1 = 0.f;
                #pragma unroll 4
                for (int p = 0; p < 128; p += 2) {
                    a0 = fmaf(e[p],   sW3[p*6+o],     a0);
                    a1 = fmaf(e[p+1], sW3[(p+1)*6+o], a1);
                }
                float acc = a0 + a1;
                if (brow) ws[OFF_B3E + (t*11+r)*8 + o] = acc;
                else      W3EB[(size_t)((t*11+r)*64 + kk)*8 + o] = bf16bits(acc);
            } else {
                int qq = q - 66;
                int sa = qq / 11, r = qq % 11;
                const float* jr = sJr + r*132;
                const float* jl = sJl + sa*132;
                float a0 = 0.f, a1 = 0.f;
                #pragma unroll 4
                for (int p = 0; p < 128; p += 2) {
                    a0 = fmaf(sWf[p],   jr[p]   * jl[p],   a0);
                    a1 = fmaf(sWf[p+1], jr[p+1] * jl[p+1], a1);
                }
                float acc = a0 + a1;
                if (brow) ws[OFF_BB + (t*11+r)*20 + sa] = acc;
                else      ws[OFF_BT + ((size_t)(t*11+r)*20 + sa)*64 + kk] = acc;
            }
        }
    }
}

// =========== K_B: CT/BC from MC histogram; -DT folded into CT/BC ==========
__global__ void k_fold(const int* __restrict__ hist, const float* __restrict__ cr,
                       float* ws) {
    int t = blockIdx.x, tid = threadIdx.x;
    unsigned short* W3EB = (unsigned short*)(ws + OFF_W3EB);
    for (int i = tid; i < 715; i += 256) {
        if (i < 704) {
            int r = i >> 6, c = i & 63;
            float crn = cr[r] * (1.0f/(float)MC);
            const float* btp = ws + OFF_BT + (size_t)(t*11+r)*20*64 + c;
            float acc = 0.f;
            #pragma unroll
            for (int sa = 0; sa < 20; ++sa)
                acc += (float)hist[r*20+sa] * btp[sa*64];
            W3EB[(size_t)((t*11+r)*64 + c)*8 + 6] = bf16bits(acc * crn * (-DT));
        } else {
            int r = i - 704;
            float crn = cr[r] * (1.0f/(float)MC);
            float acc = 0.f;
            #pragma unroll
            for (int sa = 0; sa < 20; ++sa)
                acc += (float)hist[r*20+sa] * ws[OFF_BB + (t*11+r)*20 + sa];
            ws[OFF_B3E + (t*11+r)*8 + 6] = acc * crn * (-DT);
        }
    }
}

// =========== K5: MFMA MLP; W2/W1/tables in LDS; 4 blocks/CU ===============
// Round-14 body + W1/Wf1/b1/bf1 LDS staging (3.5KB; 112 L2 global loads/g
// -> ds_reads, conflict-free broadcast pattern). No new live state in the
// main loop — same proven-safe class as the r5 tables-staging win.
// (256,4) + natural 64 VGPR: verified sweet spot, do not touch.
__launch_bounds__(256, 4)
__global__ void k_mlp(const float* __restrict__ ws,
                      const float* __restrict__ W1, const float* __restrict__ b1,
                      const float* __restrict__ Wf1, const float* __restrict__ bf1,
                      const float* __restrict__ b2, const float* __restrict__ bf2,
                      float* __restrict__ contrib) {
    __shared__ unsigned short sW2[4096], sWf2[4096];
    __shared__ unsigned short sW3E[11*520];   // r-stride 520 (pad 8)
    __shared__ float sB3E[11*12];
    __shared__ float sBB[220];
    __shared__ float sW1[384], sWf1[384], sB1[64], sBf1[64];
    int tid = threadIdx.x;
    int t = blockIdx.x & 63;
    {
        const unsigned* g2  = (const unsigned*)((const unsigned short*)(ws + OFF_W2A)  + t*4096);
        const unsigned* g2f = (const unsigned*)((const unsigned short*)(ws + OFF_WF2A) + t*4096);
        unsigned* s2  = (unsigned*)sW2;
        unsigned* s2f = (unsigned*)sWf2;
        #pragma unroll
        for (int i = 0; i < 8; ++i) {
            s2[i*256 + tid]  = g2[i*256 + tid];
            s2f[i*256 + tid] = g2f[i*256 + tid];
        }
        const unsigned* g3 = (const unsigned*)((const unsigned short*)(ws + OFF_W3EB) + (size_t)t*5632);
        unsigned* s3 = (unsigned*)sW3E;
        for (int i = tid; i < 2816; i += 256) {
            int r = i >> 8, off = i & 255;
            s3[r*260 + off] = g3[i];
        }
        if (tid < 88) {
            int r = tid >> 3, o = tid & 7;
            sB3E[r*12 + o] = ws[OFF_B3E + t*88 + tid];
        }
        if (tid < 220) sBB[tid] = ws[OFF_BB + t*220 + tid];
        for (int i = tid; i < 384; i += 256) {
            sW1[i]  = W1[t*384 + i];
            sWf1[i] = Wf1[t*384 + i];
        }
        if (tid < 64) { sB1[tid] = b1[t*64 + tid]; sBf1[tid] = bf1[t*64 + tid]; }
    }
    __syncthreads();
    int L = tid & 63, l15 = L & 15, q4 = L >> 4;
    int pbase = (blockIdx.x >> 6) * 256 + (tid >> 6) * 64;

    float4 bh4[4], bf4[4];
    #pragma unroll
    for (int ct = 0; ct < 4; ++ct) {
        bh4[ct] = *(const float4*)(b2  + t*64 + ct*16 + q4*4);
        bf4[ct] = *(const float4*)(bf2 + t*64 + ct*16 + q4*4);
    }
    const float* GEO = ws + OFF_GEO;
    const float* SM  = ws + OFF_SM;

    // prefetch g=0
    int base_n = t*BATCH + pbase + l15;
    float2 sm_n = *(const float2*)(SM + (size_t)base_n*2);
    float4 ga_n = *(const float4*)(GEO + (size_t)base_n*12);
    float4 gb_n = *(const float4*)(GEO + (size_t)base_n*12 + 4);
    float4 gc_n = *(const float4*)(GEO + (size_t)base_n*12 + 8);

    #pragma unroll 1
    for (int g = 0; g < 4; ++g) {
        int base = base_n;
        float2 sm = sm_n;
        float4 ga = ga_n, gb = gb_n, gc = gc_n;
        if (g < 3) {
            base_n = t*BATCH + pbase + (g+1)*16 + l15;
            sm_n = *(const float2*)(SM + (size_t)base_n*2);
            ga_n = *(const float4*)(GEO + (size_t)base_n*12);
            gb_n = *(const float4*)(GEO + (size_t)base_n*12 + 4);
            gc_n = *(const float4*)(GEO + (size_t)base_n*12 + 8);
        }
        float scale = sm.x;
        if (__ballot(scale != 0.f) == 0ULL) {
            if (q4 == 0) contrib[base] = 0.f;
            continue;
        }
        int meta = __float_as_int(sm.y);
        float inp[6]  = {ga.x, ga.y, ga.z, ga.w, gb.x, gb.y};
        float coef[6] = {gb.z, gb.w, gc.x, gc.y, gc.z, gc.w};
        int r = meta & 255, sa = (meta >> 8) & 255;
        bool jump = ((meta >> 16) & 1) != 0;

        // L1 -> B-fragments (B[k=q4*8+j][n=l15]); weights from LDS
        short8 bh[2], bfr[2];
        #pragma unroll
        for (int kt = 0; kt < 2; ++kt) {
            int kb = kt*32 + q4*8;
            float av[8], fv[8];
            #pragma unroll
            for (int j = 0; j < 8; ++j) { av[j] = sB1[kb+j]; fv[j] = sBf1[kb+j]; }
            #pragma unroll
            for (int i = 0; i < 6; ++i) {
                float x = inp[i];
                #pragma unroll
                for (int j = 0; j < 8; ++j) {
                    av[j] = fmaf(x, sW1[i*64 + kb + j],  av[j]);
                    fv[j] = fmaf(x, sWf1[i*64 + kb + j], fv[j]);
                }
            }
            short8 vh, vf;
            unsigned* vhp = (unsigned*)&vh;
            unsigned* vfp = (unsigned*)&vf;
            #pragma unroll
            for (int j = 0; j < 4; ++j) {
                vhp[j] = cvt_pk_bf16(tanh_f(av[2*j]), tanh_f(av[2*j+1]));
                vfp[j] = cvt_pk_bf16(tanh_f(fv[2*j]), tanh_f(fv[2*j+1]));
            }
            bh[kt] = vh; bfr[kt] = vf;
        }

        const unsigned short* W3E8 = sW3E + r*520;
        const float* btp = ws + OFF_BT + ((size_t)(t*11 + r)*20 + sa)*64;
        float pdp = 0.f;
        #pragma unroll
        for (int ct = 0; ct < 4; ++ct) {
            short8 a0 = *(const short8*)(sW2  + ((ct*2 + 0)*64 + L)*8);
            short8 a1 = *(const short8*)(sW2  + ((ct*2 + 1)*64 + L)*8);
            short8 c0 = *(const short8*)(sWf2 + ((ct*2 + 0)*64 + L)*8);
            short8 c1 = *(const short8*)(sWf2 + ((ct*2 + 1)*64 + L)*8);
            // bias as MFMA C-init (D = A*B + C): kills the post-MFMA adds
            f32x4 acc  = {bh4[ct].x, bh4[ct].y, bh4[ct].z, bh4[ct].w};
            f32x4 accf = {bf4[ct].x, bf4[ct].y, bf4[ct].z, bf4[ct].w};
            acc  = __builtin_amdgcn_mfma_f32_16x16x32_bf16(a0, bh[0],  acc,  0, 0, 0);
            acc  = __builtin_amdgcn_mfma_f32_16x16x32_bf16(a1, bh[1],  acc,  0, 0, 0);
            accf = __builtin_amdgcn_mfma_f32_16x16x32_bf16(c0, bfr[0], accf, 0, 0, 0);
            accf = __builtin_amdgcn_mfma_f32_16x16x32_bf16(c1, bfr[1], accf, 0, 0, 0);
            #pragma unroll
            for (int reg = 0; reg < 4; ++reg) {
                float h2 = tanh_f(acc[reg]);
                float f2 = tanh_f(accf[reg]);
                int c = ct*16 + q4*4 + reg;
                short8 wv = *(const short8*)(W3E8 + c*8);
                float s = bf16f((unsigned short)wv[0])*coef[0]
                        + bf16f((unsigned short)wv[1])*coef[1]
                        + bf16f((unsigned short)wv[2])*coef[2]
                        + bf16f((unsigned short)wv[3])*coef[3]
                        + bf16f((unsigned short)wv[4])*coef[4]
                        + bf16f((unsigned short)wv[5])*coef[5];
                pdp = fmaf(h2, s, pdp);
                pdp = fmaf(f2, bf16f((unsigned short)wv[6]), pdp);   // CT, -DT pre-folded
                if (jump) pdp = fmaf(f2, btp[c], pdp);
            }
        }
        pdp += __shfl_xor(pdp, 16, 64);
        pdp += __shfl_xor(pdp, 32, 64);

        const float* B3E8 = sB3E + r*12;
        float4 ba  = *(const float4*)(B3E8);
        float4 bbv = *(const float4*)(B3E8 + 4);
        float dpart = pdp
            + ba.x*coef[0] + ba.y*coef[1] + ba.z*coef[2]
            + ba.w*coef[3] + bbv.x*coef[4] + bbv.y*coef[5]
            + bbv.z;                                   // BC, -DT pre-folded
        if (jump) dpart += sBB[r*20 + sa];
        if (q4 == 0) contrib[base] = scale * dpart;
    }
}

// =========== K6: reduce over t ============================================
__global__ void k_reduce(const float* __restrict__ contrib, const float* __restrict__ u,
                         float* out) {
    __shared__ float red[256];
    int tid = threadIdx.x;
    int pi = tid & 31, tc = tid >> 5;
    int p = blockIdx.x * 32 + pi;
    float a = 0.f;
    #pragma unroll
    for (int j = 0; j < 8; ++j) a += contrib[(tc*8 + j)*BATCH + p];
    red[tid] = a;
    __syncthreads();
    if (tid < 32) {
        float s = u[0];
        #pragma unroll
        for (int c = 0; c < 8; ++c) s += red[c*32 + pi];
        out[p] = s;
    }
}

extern "C" void kernel_launch(void* const* d_in, const int* in_sizes, int n_in,
                              void* d_out, int out_size, void* d_ws, size_t ws_size,
                              hipStream_t stream) {
    const float* u      = (const float*)d_in[0];
    const float* jump_r = (const float*)d_in[1];
    const float* jump_l = (const float*)d_in[2];
    const float* W1  = (const float*)d_in[3];
    const float* b1  = (const float*)d_in[4];
    const float* W2  = (const float*)d_in[5];
    const float* b2  = (const float*)d_in[6];
    const float* W3  = (const float*)d_in[7];
    const float* b3  = (const float*)d_in[8];
    const float* emb = (const float*)d_in[9];
    const float* Wf1 = (const float*)d_in[10];
    const float* bf1 = (const float*)d_in[11];
    const float* Wf2 = (const float*)d_in[12];
    const float* bf2 = (const float*)d_in[13];
    const float* Wf3 = (const float*)d_in[14];
    const float* bf3 = (const float*)d_in[15];
    const int*   rt0 = (const int*)d_in[16];
    const float* xt0 = (const float*)d_in[17];
    const float* yt0 = (const float*)d_in[18];
    const float* dBx = (const float*)d_in[19];
    const float* dBy = (const float*)d_in[20];
    const float* junif = (const float*)d_in[21];
    const float* sunif = (const float*)d_in[22];
    const float* mcu = (const float*)d_in[23];
    const float* jm  = (const float*)d_in[24];
    const float* cr  = (const float*)d_in[25];
    const float* cfr = (const float*)d_in[26];
    float* ws  = (float*)d_ws;
    float* out = (float*)d_out;

    hipMemsetAsync(ws + OFF_HIST, 0, 220*sizeof(int), stream);
    k_prep<<<4460, 256, 0, stream>>>(rt0, xt0, yt0, dBx, dBy, junif, sunif,
                                     jm, cr, cfr, mcu, W2, Wf2,
                                     W3, b3, emb, Wf3, bf3, jump_r, jump_l,
                                     ws, (int*)(ws + OFF_HIST), out);
    k_fold<<<64, 256, 0, stream>>>((const int*)(ws + OFF_HIST), cr, ws);
    k_mlp<<<2048, 256, 0, stream>>>(ws, W1, b1, Wf1, bf1, b2, bf2,
                                    ws + OFF_CONTRIB);
    k_reduce<<<256, 256, 0, stream>>>(ws + OFF_CONTRIB, u, out);
}

// Round 16
// 259.623 us; speedup vs baseline: 1.3115x; 1.0051x over previous
//
#include <hip/hip_runtime.h>
#include <math.h>

#define NUMR 11
#define NSTEP 64
#define BATCH 8192
#define PDIM 128
#define MC 10000
#define DT (1.0f/64.0f)
#define RDOM 5.0f
#define CAP_EPS 0.1f
#define TP (NSTEP*BATCH)        // 524288

// workspace float offsets
#define OFF_HIST 0              // 220 ints
#define OFF_W3EB 256            // bf16 [t][r][c][8]: o0..5, CT(-DT folded), pad
#define OFF_B3E  180480         // f32 [t][r][8]: o0..5, BC(-DT folded), pad
#define OFF_BT   186112         // f32 [t][r][sa][c]
#define OFF_BB   1087232        // f32 [t][r][sa]
#define OFF_W2A  1101312        // bf16 A-ordered [t][4096]
#define OFF_WF2A 1232384
#define OFF_GEO  1363456        // f32 [t][p][12]
#define OFF_SM   7654912        // f32 [t][p][2] {scale, meta}
#define OFF_CONTRIB 8703488     // f32 [t][p]

typedef __attribute__((ext_vector_type(8))) short short8;   // 8 bf16
typedef __attribute__((ext_vector_type(4))) float f32x4;

// tanh via native exp2: exp(2x) = 2^(x*2log2e) — folds the *2 into the
// exp constant (one v_mul fewer per tanh; 64 tanh/lane/g in k_mlp).
__device__ __forceinline__ float tanh_f(float x) {
    float e = __builtin_amdgcn_exp2f(x * 2.885390082f);
    return 1.0f - 2.0f * __builtin_amdgcn_rcpf(e + 1.0f);
}
__device__ __forceinline__ unsigned short bf16bits(float f) {
    unsigned u = __float_as_uint(f);
    return (unsigned short)((u + 0x7FFFu + ((u >> 16) & 1u)) >> 16);
}
__device__ __forceinline__ float bf16f(unsigned short s) {
    return __uint_as_float(((unsigned)s) << 16);
}
// HW packed f32->bf16 (RNE, matches bf16bits on normals; no builtin on gfx950)
__device__ __forceinline__ unsigned cvt_pk_bf16(float lo, float hi) {
    unsigned r;
    asm("v_cvt_pk_bf16_f32 %0, %1, %2" : "=v"(r) : "v"(lo), "v"(hi));
    return r;
}

__device__ __forceinline__ void reflect3(float* p, float* g) {
    float nr = sqrtf(p[0]*p[0] + p[1]*p[1] + p[2]*p[2]);
    if (nr > RDOM) {
        float inv = 1.0f / fmaxf(nr, 1e-12f);   // exact div: trajectory-sensitive
        float nb0 = p[0]*inv, nb1 = p[1]*inv, nb2 = p[2]*inv;
        float sc = 2.0f*RDOM - nr;
        p[0] = nb0*sc; p[1] = nb1*sc; p[2] = nb2*sc;
        #pragma unroll
        for (int j = 0; j < 3; ++j) {
            float proj = nb0*g[j] + nb1*g[3+j] + nb2*g[6+j];
            g[j]   -= 2.0f*nb0*proj;
            g[3+j] -= 2.0f*nb1*proj;
            g[6+j] -= 2.0f*nb2*proj;
        }
    }
}

// =========== K_A: fused prep ==============================================
// [0,128): geom | [128,236): hist | [236,300): pack | [300,4460): tables.
// Geom: 2-step-deep input prefetch (per-step compute ~600cy < HBM ~900cy).
// Tables branch LDS-stages all dot-product inputs; strides padded to 132.
__launch_bounds__(256)
__global__ void k_prep(const int* __restrict__ rt0, const float* __restrict__ xt0,
                       const float* __restrict__ yt0, const float* __restrict__ dBx,
                       const float* __restrict__ dBy, const float* __restrict__ junif,
                       const float* __restrict__ sunif, const float* __restrict__ jm,
                       const float* __restrict__ cr, const float* __restrict__ cfr,
                       const float* __restrict__ mcu,
                       const float* __restrict__ W2, const float* __restrict__ Wf2,
                       const float* __restrict__ W3, const float* __restrict__ b3,
                       const float* __restrict__ emb, const float* __restrict__ Wf3,
                       const float* __restrict__ bf3, const float* __restrict__ jump_r,
                       const float* __restrict__ jump_l,
                       float* ws, int* hist, float* out) {
    // overlaid LDS: tables use 6440 floats; geom uses 242; hist uses 220 ints
    __shared__ float smem[6440];
    int blk = blockIdx.x, tid = threadIdx.x;

    if (blk < 128) {
        // ---------------- geom: 1 particle/thread, 64 working lanes -------
        float* sjm = smem; float* scr = smem + 220; float* smul = smem + 231;
        for (int i = tid; i < 220; i += 256) sjm[i] = jm[i];
        if (tid < 11) { scr[tid] = cr[tid]; smul[tid] = __expf(-cfr[tid]*DT); }
        __syncthreads();
        if (tid >= 64) return;
        int p = blk * 64 + tid;

        int rt = rt0[p];
        float xt[3], xin[3], yin[3], gtx[9], gty[9];
        #pragma unroll
        for (int i = 0; i < 3; ++i) { xt[i] = xt0[p*3+i]; xin[i] = xt[i]; yin[i] = yt0[p*3+i]; }
        #pragma unroll
        for (int i = 0; i < 9; ++i) { gtx[i] = (i % 4 == 0) ? 1.f : 0.f; gty[i] = gtx[i]; }
        float ef = 1.f, run = 1.f;

        // cur = t=0, nxt = t=1 (prefetched); loop issues t+2 at top of t
        float ju = junif[p], su = sunif[p];
        float dbx0 = dBx[(size_t)p*2], dbx1 = dBx[(size_t)p*2+1];
        float dby0 = dBy[(size_t)p*3], dby1 = dBy[(size_t)p*3+1], dby2 = dBy[(size_t)p*3+2];
        float nju=0.f,nsu=0.f,ndbx0=0.f,ndbx1=0.f,ndby0=0.f,ndby1=0.f,ndby2=0.f;
        {
            int nb = BATCH + p;
            nju = junif[nb]; nsu = sunif[nb];
            ndbx0 = dBx[(size_t)nb*2]; ndbx1 = dBx[(size_t)nb*2+1];
            ndby0 = dBy[(size_t)nb*3]; ndby1 = dBy[(size_t)nb*3+1]; ndby2 = dBy[(size_t)nb*3+2];
        }

        float* GEO = ws + OFF_GEO;
        float* SM  = ws + OFF_SM;
        #pragma unroll 1
        for (int t = 0; t < NSTEP; ++t) {
            float mju=0.f,msu=0.f,mdbx0=0.f,mdbx1=0.f,mdby0=0.f,mdby1=0.f,mdby2=0.f;
            if (t < NSTEP-2) {
                int nb = (t+2)*BATCH + p;
                mju = junif[nb]; msu = sunif[nb];
                mdbx0 = dBx[(size_t)nb*2]; mdbx1 = dBx[(size_t)nb*2+1];
                mdby0 = dBy[(size_t)nb*3]; mdby1 = dBy[(size_t)nb*3+1]; mdby2 = dBy[(size_t)nb*3+2];
            }
            int base = t*BATCH + p;
            int r = rt - 10;
            int jon = (ju < scr[r]*DT) ? 1 : 0;
            int cnt = 0;
            #pragma unroll
            for (int j = 0; j < 20; ++j) cnt += (su < sjm[r*20+j]) ? 1 : 0;
            int ind = 20 - cnt;
            int drt = (ind < 10) ? (ind+1) : -(ind-9);
            drt = jon ? drt : 0;
            int sa = (drt > 0) ? (drt-1) : ((drt < 0) ? (9-drt) : 0);
            int jf = (drt != 0) ? 1 : 0;

            float nx = fmaxf(sqrtf(xt[0]*xt[0]+xt[1]*xt[1]+xt[2]*xt[2]), 1e-12f);
            float c = fminf(1.f, fmaxf(-1.f, xt[2]/nx));
            float ct = sqrtf(fmaxf(0.f, 1.f - c*c));
            float st = -c;
            float rxy2 = xt[0]*xt[0] + xt[1]*xt[1];
            float cp = 1.f, sp = 0.f;
            if (rxy2 > 0.f) { float ir = 1.0f/sqrtf(rxy2); cp = xt[0]*ir; sp = xt[1]*ir; }
            float Ti[9];
            Ti[0]=cp*ct; Ti[1]=-sp; Ti[2]=cp*st;
            Ti[3]=sp*ct; Ti[4]=cp;  Ti[5]=sp*st;
            Ti[6]=-st;   Ti[7]=0.f; Ti[8]=ct;

            float sdx = 1.0f/(float)(r+10);
            float scale = run * ef;

            float cx[3], cy[3];
            #pragma unroll
            for (int i = 0; i < 3; ++i) {
                float w31 = gtx[i*3]*Ti[1] + gtx[i*3+1]*Ti[4] + gtx[i*3+2]*Ti[7];
                float w32 = gtx[i*3]*Ti[2] + gtx[i*3+1]*Ti[5] + gtx[i*3+2]*Ti[8];
                cx[i] = sdx * (w31*dbx1 - w32*dbx0);
                cy[i] = gty[i*3]*dby0 + gty[i*3+1]*dby1 + gty[i*3+2]*dby2;
            }
            float* gp = GEO + (size_t)base*12;
            float4 v0 = {xin[0], xin[1], xin[2], yin[0]};
            float4 v1 = {yin[1], yin[2], cx[0], cx[1]};
            float4 v2 = {cx[2], cy[0], cy[1], cy[2]};
            *(float4*)(gp)     = v0;
            *(float4*)(gp + 4) = v1;
            *(float4*)(gp + 8) = v2;
            float2 smv = {scale, __int_as_float(r | (sa<<8) | (jf<<16))};
            *(float2*)(SM + (size_t)base*2) = smv;

            ef *= smul[r];

            // Taylor sin/cos: |dX| <= ~0.075, err ~8e-9
            float dX0 = sdx*dbx0, dX1 = sdx*dbx1;
            float x2 = dX0*dX0, y2 = dX1*dX1;
            float s0 = dX0*(1.f - x2*(1.f/6.f));
            float cc0 = 1.f - x2*0.5f + x2*x2*(1.f/24.f);
            float s1 = dX1*(1.f - y2*(1.f/6.f));
            float cc1 = 1.f - y2*0.5f + y2*y2*(1.f/24.f);
            float cart0 = cc0*cc1 - 1.0f, cart1 = cc0*s1, cart2 = -s0;
            float dX3[3];
            #pragma unroll
            for (int i = 0; i < 3; ++i)
                dX3[i] = Ti[i*3]*cart0 + Ti[i*3+1]*cart1 + Ti[i*3+2]*cart2;
            #pragma unroll
            for (int i = 0; i < 3; ++i) xt[i] += dX3[i];
            #pragma unroll
            for (int i = 0; i < 3; ++i)
                xin[i] += gtx[i*3]*dX3[0] + gtx[i*3+1]*dX3[1] + gtx[i*3+2]*dX3[2];
            #pragma unroll
            for (int i = 0; i < 3; ++i)
                yin[i] += gty[i*3]*dby0 + gty[i*3+1]*dby1 + gty[i*3+2]*dby2;
            rt += drt; rt = (rt < 10) ? 10 : ((rt > 20) ? 20 : rt);
            reflect3(xin, gtx);
            reflect3(yin, gty);
            float d0 = xin[0]-yin[0], d1 = xin[1]-yin[1], d2 = xin[2]-yin[2];
            if (sqrtf(d0*d0 + d1*d1 + d2*d2) < CAP_EPS) run = 0.f;

            ju = nju; su = nsu; dbx0 = ndbx0; dbx1 = ndbx1;
            dby0 = ndby0; dby1 = ndby1; dby2 = ndby2;
            nju = mju; nsu = msu; ndbx0 = mdbx0; ndbx1 = mdbx1;
            ndby0 = mdby0; ndby1 = mdby1; ndby2 = mdby2;
        }
        float d0 = xin[0]-yin[0], d1 = xin[1]-yin[1], d2 = xin[2]-yin[2];
        float u0v = __expf(-(d0*d0 + d1*d1 + d2*d2));
        out[BATCH + p] = run * u0v * ef;

    } else if (blk < 236) {
        // ---------------- hist ----------------
        int* lh = (int*)smem;
        for (int i = tid; i < 220; i += 256) lh[i] = 0;
        __syncthreads();
        int hb = blk - 128;
        #pragma unroll
        for (int j = 0; j < 4; ++j) {
            int i = hb*1024 + j*256 + tid;
            if (i < MC*NUMR) {
                int r = i % NUMR;
                float u = mcu[i];
                int cnt = 0;
                #pragma unroll
                for (int k = 0; k < 20; ++k) cnt += (u < jm[r*20+k]) ? 1 : 0;
                int ind = 20 - cnt;
                int s = (ind < 10) ? (ind+1) : -(ind-9);
                int sa = (s > 0) ? (s-1) : (10 + (-s-1));
                atomicAdd(&lh[r*20+sa], 1);
            }
        }
        __syncthreads();
        if (tid < 220 && lh[tid]) atomicAdd(&hist[tid], lh[tid]);

    } else if (blk < 300) {
        // ---------------- pack W2/Wf2 -> bf16 MFMA-A-lane order -----------
        int t = blk - 236;
        unsigned short* W2A  = (unsigned short*)(ws + OFF_W2A)  + t*4096;
        unsigned short* WF2A = (unsigned short*)(ws + OFF_WF2A) + t*4096;
        for (int i = tid; i < 4096; i += 256) {
            int j = i & 7, L = (i >> 3) & 63, ktct = i >> 9;
            int ct = ktct >> 1, kt = ktct & 1;
            int c = ct*16 + (L & 15);
            int k = kt*32 + (L >> 4)*8 + j;
            W2A[i]  = bf16bits(W2[t*4096 + k*64 + c]);
            WF2A[i] = bf16bits(Wf2[t*4096 + k*64 + c]);
        }

    } else {
        // ---------------- tables (W3E slots 0-5 bf16, B3E, BT, BB) --------
        // LDS-staged inputs; identical FP order to the global-load version.
        int idx = blk - 300;
        int t = idx / 65, kk = idx % 65;
        bool brow = (kk == 64);
        const float* w3row = brow ? (b3 + t*768) : (W3 + (t*64+kk)*768);
        const float* wfrow = brow ? (bf3 + t*128) : (Wf3 + (t*64+kk)*128);
        unsigned short* W3EB = (unsigned short*)(ws + OFF_W3EB);

        float* sW3  = smem;          // 768
        float* sWf  = smem + 768;    // 128
        float* sEmb = smem + 896;    // 11*132 = 1452
        float* sJr  = smem + 2348;   // 11*132 = 1452
        float* sJl  = smem + 3800;   // 20*132 = 2640  (total 6440)
        for (int i = tid; i < 768; i += 256) sW3[i] = w3row[i];
        if (tid < 128) sWf[tid] = wfrow[tid];
        for (int i = tid; i < 1408; i += 256) {
            int r = i >> 7, p = i & 127;
            sEmb[r*132 + p] = emb[(t*11+r)*128 + p];
            sJr[r*132 + p]  = jump_r[i];
        }
        for (int i = tid; i < 2560; i += 256) {
            int sa = i >> 7, p = i & 127;
            sJl[sa*132 + p] = jump_l[i];
        }
        __syncthreads();

        for (int q = tid; q < 286; q += 256) {
            if (q < 66) {
                int o = q / 11, r = q % 11;
                const float* e = sEmb + r*132;
                float a0 = 0.f, a1 = 0.f;
                #pragma unroll 4
                for (int p = 0; p < 128; p += 2) {
                    a0 = fmaf(e[p],   sW3[p*6+o],     a0);
                    a1 = fmaf(e[p+1], sW3[(p+1)*6+o], a1);
                }
                float acc = a0 + a1;
                if (brow) ws[OFF_B3E + (t*11+r)*8 + o] = acc;
                else      W3EB[(size_t)((t*11+r)*64 + kk)*8 + o] = bf16bits(acc);
            } else {
                int qq = q - 66;
                int sa = qq / 11, r = qq % 11;
                const float* jr = sJr + r*132;
                const float* jl = sJl + sa*132;
                float a0 = 0.f, a1 = 0.f;
                #pragma unroll 4
                for (int p = 0; p < 128; p += 2) {
                    a0 = fmaf(sWf[p],   jr[p]   * jl[p],   a0);
                    a1 = fmaf(sWf[p+1], jr[p+1] * jl[p+1], a1);
                }
                float acc = a0 + a1;
                if (brow) ws[OFF_BB + (t*11+r)*20 + sa] = acc;
                else      ws[OFF_BT + ((size_t)(t*11+r)*20 + sa)*64 + kk] = acc;
            }
        }
    }
}

// =========== K_B: CT/BC from MC histogram; -DT folded into CT/BC ==========
__global__ void k_fold(const int* __restrict__ hist, const float* __restrict__ cr,
                       float* ws) {
    int t = blockIdx.x, tid = threadIdx.x;
    unsigned short* W3EB = (unsigned short*)(ws + OFF_W3EB);
    for (int i = tid; i < 715; i += 256) {
        if (i < 704) {
            int r = i >> 6, c = i & 63;
            float crn = cr[r] * (1.0f/(float)MC);
            const float* btp = ws + OFF_BT + (size_t)(t*11+r)*20*64 + c;
            float acc = 0.f;
            #pragma unroll
            for (int sa = 0; sa < 20; ++sa)
                acc += (float)hist[r*20+sa] * btp[sa*64];
            W3EB[(size_t)((t*11+r)*64 + c)*8 + 6] = bf16bits(acc * crn * (-DT));
        } else {
            int r = i - 704;
            float crn = cr[r] * (1.0f/(float)MC);
            float acc = 0.f;
            #pragma unroll
            for (int sa = 0; sa < 20; ++sa)
                acc += (float)hist[r*20+sa] * ws[OFF_BB + (t*11+r)*20 + sa];
            ws[OFF_B3E + (t*11+r)*8 + 6] = acc * crn * (-DT);
        }
    }
}

// =========== K5: MFMA MLP; W2/W1/tables in LDS; 5 blocks/CU ===============
// Round-15 body; only change: sB3E stride 12->8 floats (-176 B) brings raw
// LDS to 32640 -> allocation exactly 32768 B -> floor(160K/32K) = 5 blocks/CU
// from HW LDS limit alone (launch_bounds hint untouched — the (256,5)/none
// allocator poisons don't apply; VGPR stays 64, 8 waves/SIMD allowed).
__launch_bounds__(256, 4)
__global__ void k_mlp(const float* __restrict__ ws,
                      const float* __restrict__ W1, const float* __restrict__ b1,
                      const float* __restrict__ Wf1, const float* __restrict__ bf1,
                      const float* __restrict__ b2, const float* __restrict__ bf2,
                      float* __restrict__ contrib) {
    __shared__ unsigned short sW2[4096], sWf2[4096];
    __shared__ unsigned short sW3E[11*520];   // r-stride 520 (pad 8)
    __shared__ float sB3E[11*8];              // natural [r][8] stride
    __shared__ float sBB[220];
    __shared__ float sW1[384], sWf1[384], sB1[64], sBf1[64];
    int tid = threadIdx.x;
    int t = blockIdx.x & 63;
    {
        const unsigned* g2  = (const unsigned*)((const unsigned short*)(ws + OFF_W2A)  + t*4096);
        const unsigned* g2f = (const unsigned*)((const unsigned short*)(ws + OFF_WF2A) + t*4096);
        unsigned* s2  = (unsigned*)sW2;
        unsigned* s2f = (unsigned*)sWf2;
        #pragma unroll
        for (int i = 0; i < 8; ++i) {
            s2[i*256 + tid]  = g2[i*256 + tid];
            s2f[i*256 + tid] = g2f[i*256 + tid];
        }
        const unsigned* g3 = (const unsigned*)((const unsigned short*)(ws + OFF_W3EB) + (size_t)t*5632);
        unsigned* s3 = (unsigned*)sW3E;
        for (int i = tid; i < 2816; i += 256) {
            int r = i >> 8, off = i & 255;
            s3[r*260 + off] = g3[i];
        }
        if (tid < 88) sB3E[tid] = ws[OFF_B3E + t*88 + tid];   // [r][8] direct
        if (tid < 220) sBB[tid] = ws[OFF_BB + t*220 + tid];
        for (int i = tid; i < 384; i += 256) {
            sW1[i]  = W1[t*384 + i];
            sWf1[i] = Wf1[t*384 + i];
        }
        if (tid < 64) { sB1[tid] = b1[t*64 + tid]; sBf1[tid] = bf1[t*64 + tid]; }
    }
    __syncthreads();
    int L = tid & 63, l15 = L & 15, q4 = L >> 4;
    int pbase = (blockIdx.x >> 6) * 256 + (tid >> 6) * 64;

    float4 bh4[4], bf4[4];
    #pragma unroll
    for (int ct = 0; ct < 4; ++ct) {
        bh4[ct] = *(const float4*)(b2  + t*64 + ct*16 + q4*4);
        bf4[ct] = *(const float4*)(bf2 + t*64 + ct*16 + q4*4);
    }
    const float* GEO = ws + OFF_GEO;
    const float* SM  = ws + OFF_SM;

    // prefetch g=0
    int base_n = t*BATCH + pbase + l15;
    float2 sm_n = *(const float2*)(SM + (size_t)base_n*2);
    float4 ga_n = *(const float4*)(GEO + (size_t)base_n*12);
    float4 gb_n = *(const float4*)(GEO + (size_t)base_n*12 + 4);
    float4 gc_n = *(const float4*)(GEO + (size_t)base_n*12 + 8);

    #pragma unroll 1
    for (int g = 0; g < 4; ++g) {
        int base = base_n;
        float2 sm = sm_n;
        float4 ga = ga_n, gb = gb_n, gc = gc_n;
        if (g < 3) {
            base_n = t*BATCH + pbase + (g+1)*16 + l15;
            sm_n = *(const float2*)(SM + (size_t)base_n*2);
            ga_n = *(const float4*)(GEO + (size_t)base_n*12);
            gb_n = *(const float4*)(GEO + (size_t)base_n*12 + 4);
            gc_n = *(const float4*)(GEO + (size_t)base_n*12 + 8);
        }
        float scale = sm.x;
        if (__ballot(scale != 0.f) == 0ULL) {
            if (q4 == 0) contrib[base] = 0.f;
            continue;
        }
        int meta = __float_as_int(sm.y);
        float inp[6]  = {ga.x, ga.y, ga.z, ga.w, gb.x, gb.y};
        float coef[6] = {gb.z, gb.w, gc.x, gc.y, gc.z, gc.w};
        int r = meta & 255, sa = (meta >> 8) & 255;
        bool jump = ((meta >> 16) & 1) != 0;

        // L1 -> B-fragments (B[k=q4*8+j][n=l15]); weights from LDS
        short8 bh[2], bfr[2];
        #pragma unroll
        for (int kt = 0; kt < 2; ++kt) {
            int kb = kt*32 + q4*8;
            float av[8], fv[8];
            #pragma unroll
            for (int j = 0; j < 8; ++j) { av[j] = sB1[kb+j]; fv[j] = sBf1[kb+j]; }
            #pragma unroll
            for (int i = 0; i < 6; ++i) {
                float x = inp[i];
                #pragma unroll
                for (int j = 0; j < 8; ++j) {
                    av[j] = fmaf(x, sW1[i*64 + kb + j],  av[j]);
                    fv[j] = fmaf(x, sWf1[i*64 + kb + j], fv[j]);
                }
            }
            short8 vh, vf;
            unsigned* vhp = (unsigned*)&vh;
            unsigned* vfp = (unsigned*)&vf;
            #pragma unroll
            for (int j = 0; j < 4; ++j) {
                vhp[j] = cvt_pk_bf16(tanh_f(av[2*j]), tanh_f(av[2*j+1]));
                vfp[j] = cvt_pk_bf16(tanh_f(fv[2*j]), tanh_f(fv[2*j+1]));
            }
            bh[kt] = vh; bfr[kt] = vf;
        }

        const unsigned short* W3E8 = sW3E + r*520;
        const float* btp = ws + OFF_BT + ((size_t)(t*11 + r)*20 + sa)*64;
        float pdp = 0.f;
        #pragma unroll
        for (int ct = 0; ct < 4; ++ct) {
            short8 a0 = *(const short8*)(sW2  + ((ct*2 + 0)*64 + L)*8);
            short8 a1 = *(const short8*)(sW2  + ((ct*2 + 1)*64 + L)*8);
            short8 c0 = *(const short8*)(sWf2 + ((ct*2 + 0)*64 + L)*8);
            short8 c1 = *(const short8*)(sWf2 + ((ct*2 + 1)*64 + L)*8);
            // bias as MFMA C-init (D = A*B + C): kills the post-MFMA adds
            f32x4 acc  = {bh4[ct].x, bh4[ct].y, bh4[ct].z, bh4[ct].w};
            f32x4 accf = {bf4[ct].x, bf4[ct].y, bf4[ct].z, bf4[ct].w};
            acc  = __builtin_amdgcn_mfma_f32_16x16x32_bf16(a0, bh[0],  acc,  0, 0, 0);
            acc  = __builtin_amdgcn_mfma_f32_16x16x32_bf16(a1, bh[1],  acc,  0, 0, 0);
            accf = __builtin_amdgcn_mfma_f32_16x16x32_bf16(c0, bfr[0], accf, 0, 0, 0);
            accf = __builtin_amdgcn_mfma_f32_16x16x32_bf16(c1, bfr[1], accf, 0, 0, 0);
            #pragma unroll
            for (int reg = 0; reg < 4; ++reg) {
                float h2 = tanh_f(acc[reg]);
                float f2 = tanh_f(accf[reg]);
                int c = ct*16 + q4*4 + reg;
                short8 wv = *(const short8*)(W3E8 + c*8);
                float s = bf16f((unsigned short)wv[0])*coef[0]
                        + bf16f((unsigned short)wv[1])*coef[1]
                        + bf16f((unsigned short)wv[2])*coef[2]
                        + bf16f((unsigned short)wv[3])*coef[3]
                        + bf16f((unsigned short)wv[4])*coef[4]
                        + bf16f((unsigned short)wv[5])*coef[5];
                pdp = fmaf(h2, s, pdp);
                pdp = fmaf(f2, bf16f((unsigned short)wv[6]), pdp);   // CT, -DT pre-folded
                if (jump) pdp = fmaf(f2, btp[c], pdp);
            }
        }
        pdp += __shfl_xor(pdp, 16, 64);
        pdp += __shfl_xor(pdp, 32, 64);

        const float* B3E8 = sB3E + r*8;
        float4 ba  = *(const float4*)(B3E8);
        float4 bbv = *(const float4*)(B3E8 + 4);
        float dpart = pdp
            + ba.x*coef[0] + ba.y*coef[1] + ba.z*coef[2]
            + ba.w*coef[3] + bbv.x*coef[4] + bbv.y*coef[5]
            + bbv.z;                                   // BC, -DT pre-folded
        if (jump) dpart += sBB[r*20 + sa];
        if (q4 == 0) contrib[base] = scale * dpart;
    }
}

// =========== K6: reduce over t ============================================
__global__ void k_reduce(const float* __restrict__ contrib, const float* __restrict__ u,
                         float* out) {
    __shared__ float red[256];
    int tid = threadIdx.x;
    int pi = tid & 31, tc = tid >> 5;
    int p = blockIdx.x * 32 + pi;
    float a = 0.f;
    #pragma unroll
    for (int j = 0; j < 8; ++j) a += contrib[(tc*8 + j)*BATCH + p];
    red[tid] = a;
    __syncthreads();
    if (tid < 32) {
        float s = u[0];
        #pragma unroll
        for (int c = 0; c < 8; ++c) s += red[c*32 + pi];
        out[p] = s;
    }
}

extern "C" void kernel_launch(void* const* d_in, const int* in_sizes, int n_in,
                              void* d_out, int out_size, void* d_ws, size_t ws_size,
                              hipStream_t stream) {
    const float* u      = (const float*)d_in[0];
    const float* jump_r = (const float*)d_in[1];
    const float* jump_l = (const float*)d_in[2];
    const float* W1  = (const float*)d_in[3];
    const float* b1  = (const float*)d_in[4];
    const float* W2  = (const float*)d_in[5];
    const float* b2  = (const float*)d_in[6];
    const float* W3  = (const float*)d_in[7];
    const float* b3  = (const float*)d_in[8];
    const float* emb = (const float*)d_in[9];
    const float* Wf1 = (const float*)d_in[10];
    const float* bf1 = (const float*)d_in[11];
    const float* Wf2 = (const float*)d_in[12];
    const float* bf2 = (const float*)d_in[13];
    const float* Wf3 = (const float*)d_in[14];
    const float* bf3 = (const float*)d_in[15];
    const int*   rt0 = (const int*)d_in[16];
    const float* xt0 = (const float*)d_in[17];
    const float* yt0 = (const float*)d_in[18];
    const float* dBx = (const float*)d_in[19];
    const float* dBy = (const float*)d_in[20];
    const float* junif = (const float*)d_in[21];
    const float* sunif = (const float*)d_in[22];
    const float* mcu = (const float*)d_in[23];
    const float* jm  = (const float*)d_in[24];
    const float* cr  = (const float*)d_in[25];
    const float* cfr = (const float*)d_in[26];
    float* ws  = (float*)d_ws;
    float* out = (float*)d_out;

    hipMemsetAsync(ws + OFF_HIST, 0, 220*sizeof(int), stream);
    k_prep<<<4460, 256, 0, stream>>>(rt0, xt0, yt0, dBx, dBy, junif, sunif,
                                     jm, cr, cfr, mcu, W2, Wf2,
                                     W3, b3, emb, Wf3, bf3, jump_r, jump_l,
                                     ws, (int*)(ws + OFF_HIST), out);
    k_fold<<<64, 256, 0, stream>>>((const int*)(ws + OFF_HIST), cr, ws);
    k_mlp<<<2048, 256, 0, stream>>>(ws, W1, b1, Wf1, bf1, b2, bf2,
                                    ws + OFF_CONTRIB);
    k_reduce<<<256, 256, 0, stream>>>(ws + OFF_CONTRIB, u, out);
}